// Round 17
// baseline (1428.156 us; speedup 1.0000x reference)
//
#include <hip/hip_runtime.h>
#include <hip/hip_bf16.h>
#include <cstdint>
#include <cstddef>

// ---- Model constants ----
#define Dm   768
#define NHm  12
#define Lm   4
#define Em   8
#define Vm   50257
#define Hm   3072
#define Tm   512
#define Bm   2
#define NT   (Bm*Tm)      // 1024 tokens
#define NAS  (NT*2)       // 2048 expert assignments

typedef float f32x4 __attribute__((ext_vector_type(4)));
typedef short bf16x8 __attribute__((ext_vector_type(8)));

__device__ __forceinline__ float gelu_exact(float x) {
    return 0.5f * x * (1.0f + erff(x * 0.70710678118654752440f));
}

__device__ __forceinline__ unsigned short f2bf(float f) {
    __hip_bfloat16 h = __float2bfloat16(f);
    union { __hip_bfloat16 h; unsigned short s; } c; c.h = h; return c.s;
}
__device__ __forceinline__ float bf2f_bits(unsigned short b) {
    union { unsigned u; float f; } c; c.u = ((unsigned)b) << 16; return c.f;
}

// ---------------- fp32 -> bf16 bulk convert (emb only) ----------------
__global__ __launch_bounds__(256) void cvt_bf16_kernel(const float* __restrict__ in,
                                                       unsigned short* __restrict__ out,
                                                       long n) {
    long i = ((long)blockIdx.x * 256 + threadIdx.x) * 8;
    if (i + 8 <= n) {
        const float4* s4 = reinterpret_cast<const float4*>(in + i);
        float4 f0 = s4[0], f1 = s4[1];
        union { unsigned short s[8]; uint4 v; } p;
        p.s[0] = f2bf(f0.x); p.s[1] = f2bf(f0.y); p.s[2] = f2bf(f0.z); p.s[3] = f2bf(f0.w);
        p.s[4] = f2bf(f1.x); p.s[5] = f2bf(f1.y); p.s[6] = f2bf(f1.z); p.s[7] = f2bf(f1.w);
        *reinterpret_cast<uint4*>(out + i) = p.v;
    } else {
        for (long j = i; j < n; ++j) out[j] = f2bf(in[j]);
    }
}

// ---------------- Embedding + sinusoidal PE ----------------
__global__ __launch_bounds__(256) void embed_kernel(const int* __restrict__ x,
                                                    const float* __restrict__ emb,
                                                    float* __restrict__ h) {
    int g = blockIdx.x;
    int tid = threadIdx.x;
    int tok = x[g];
    int pos = g % Tm;
    const float* erow = emb + (size_t)tok * Dm;
    for (int d = tid; d < Dm; d += 256) {
        int i2 = (d >> 1) * 2;
        float div = expf(-logf(10000.0f) * (float)i2 / (float)Dm);
        float a = (float)pos * div;
        float pe = (d & 1) ? cosf(a) : sinf(a);
        h[(size_t)g * Dm + d] = erow[d] + pe;
    }
}

// ---------------- LayerNorm: fp32 xn + hi/lo bf16 split ----------------
__global__ __launch_bounds__(256) void ln_kernel(const float* __restrict__ in,
                                                 const float* __restrict__ g,
                                                 const float* __restrict__ b,
                                                 float* __restrict__ xn,
                                                 unsigned short* __restrict__ xnh,
                                                 unsigned short* __restrict__ xnl) {
    int t = blockIdx.x, tid = threadIdx.x;
    const float* x = in + (size_t)t * Dm;
    float v0 = x[tid], v1 = x[tid + 256], v2 = x[tid + 512];
    __shared__ float red[256];
    red[tid] = v0 + v1 + v2;
    __syncthreads();
    for (int off = 128; off > 0; off >>= 1) {
        if (tid < off) red[tid] += red[tid + off];
        __syncthreads();
    }
    float mean = red[0] * (1.0f / Dm);
    __syncthreads();
    float d0 = v0 - mean, d1 = v1 - mean, d2 = v2 - mean;
    red[tid] = d0 * d0 + d1 * d1 + d2 * d2;
    __syncthreads();
    for (int off = 128; off > 0; off >>= 1) {
        if (tid < off) red[tid] += red[tid + off];
        __syncthreads();
    }
    float inv = rsqrtf(red[0] * (1.0f / Dm) + 1e-5f);
    float o0 = d0 * inv * g[tid]       + b[tid];
    float o1 = d1 * inv * g[tid + 256] + b[tid + 256];
    float o2 = d2 * inv * g[tid + 512] + b[tid + 512];
    long base = (size_t)t * Dm;
    xn[base + tid] = o0; xn[base + tid + 256] = o1; xn[base + tid + 512] = o2;
    unsigned short h0 = f2bf(o0), h1 = f2bf(o1), h2 = f2bf(o2);
    xnh[base + tid] = h0; xnh[base + tid + 256] = h1; xnh[base + tid + 512] = h2;
    xnl[base + tid]       = f2bf(o0 - bf2f_bits(h0));
    xnl[base + tid + 256] = f2bf(o1 - bf2f_bits(h1));
    xnl[base + tid + 512] = f2bf(o2 - bf2f_bits(h2));
}

// ============ MFMA GEMM machinery ============
#define MB 128
#define NB 128
#define KB 32
#define LDT 40

__device__ __forceinline__ void stage_tile(unsigned short* lds, const float* src,
                                           bool valid, int srow, int shalf) {
    union { unsigned short s[8]; uint4 v; } p0, p1;
    if (valid) {
        const float4* s4 = reinterpret_cast<const float4*>(src);
        #pragma unroll
        for (int q = 0; q < 4; ++q) {
            float4 f = s4[q];
            float vv[4] = {f.x, f.y, f.z, f.w};
            #pragma unroll
            for (int j = 0; j < 4; ++j) {
                int idx = q * 4 + j;
                unsigned short hb = f2bf(vv[j]);
                if (idx < 8) p0.s[idx] = hb; else p1.s[idx - 8] = hb;
            }
        }
    } else {
        p0.v = make_uint4(0, 0, 0, 0);
        p1.v = make_uint4(0, 0, 0, 0);
    }
    uint4* dst = reinterpret_cast<uint4*>(&lds[srow * LDT + shalf * 16]);
    dst[0] = p0.v; dst[1] = p1.v;
}

__device__ __forceinline__ void stage_tile_split(unsigned short* lds_hi,
                                                 unsigned short* lds_lo,
                                                 const float* src,
                                                 bool valid, int srow, int shalf) {
    union { unsigned short s[8]; uint4 v; } h0, h1, l0, l1;
    if (valid) {
        const float4* s4 = reinterpret_cast<const float4*>(src);
        #pragma unroll
        for (int q = 0; q < 4; ++q) {
            float4 f = s4[q];
            float vv[4] = {f.x, f.y, f.z, f.w};
            #pragma unroll
            for (int j = 0; j < 4; ++j) {
                int idx = q * 4 + j;
                unsigned short hb = f2bf(vv[j]);
                unsigned short lb = f2bf(vv[j] - bf2f_bits(hb));
                if (idx < 8) { h0.s[idx] = hb; l0.s[idx] = lb; }
                else         { h1.s[idx - 8] = hb; l1.s[idx - 8] = lb; }
            }
        }
    } else {
        h0.v = make_uint4(0,0,0,0); h1.v = make_uint4(0,0,0,0);
        l0.v = make_uint4(0,0,0,0); l1.v = make_uint4(0,0,0,0);
    }
    uint4* dh = reinterpret_cast<uint4*>(&lds_hi[srow * LDT + shalf * 16]);
    dh[0] = h0.v; dh[1] = h1.v;
    uint4* dl = reinterpret_cast<uint4*>(&lds_lo[srow * LDT + shalf * 16]);
    dl[0] = l0.v; dl[1] = l1.v;
}

// Split 16 fp32 held in registers -> hi/lo bf16 LDS.
__device__ __forceinline__ void stage_split_regs(unsigned short* lds_hi,
                                                 unsigned short* lds_lo,
                                                 const float4* rv,
                                                 int srow, int shalf) {
    union { unsigned short s[8]; uint4 v; } h0, h1, l0, l1;
    #pragma unroll
    for (int q = 0; q < 4; ++q) {
        float vv[4] = {rv[q].x, rv[q].y, rv[q].z, rv[q].w};
        #pragma unroll
        for (int j = 0; j < 4; ++j) {
            int idx = q * 4 + j;
            unsigned short hb = f2bf(vv[j]);
            unsigned short lb = f2bf(vv[j] - bf2f_bits(hb));
            if (idx < 8) { h0.s[idx] = hb; l0.s[idx] = lb; }
            else         { h1.s[idx - 8] = hb; l1.s[idx - 8] = lb; }
        }
    }
    uint4* dh = reinterpret_cast<uint4*>(&lds_hi[srow * LDT + shalf * 16]);
    dh[0] = h0.v; dh[1] = h1.v;
    uint4* dl = reinterpret_cast<uint4*>(&lds_lo[srow * LDT + shalf * 16]);
    dl[0] = l0.v; dl[1] = l1.v;
}

// Copy 16 pre-split bf16 into LDS (pure uint4 copies).
__device__ __forceinline__ void stage_tile_copy(unsigned short* lds,
                                                const unsigned short* src,
                                                bool valid, int srow, int shalf) {
    uint4 a0 = make_uint4(0,0,0,0), a1 = make_uint4(0,0,0,0);
    if (valid) {
        a0 = reinterpret_cast<const uint4*>(src)[0];
        a1 = reinterpret_cast<const uint4*>(src)[1];
    }
    uint4* d = reinterpret_cast<uint4*>(&lds[srow * LDT + shalf * 16]);
    d[0] = a0; d[1] = a1;
}

// ---- Lean all-bf16 MFMA GEMM (logits): XCD swizzle + DEPTH-2 register
// prefetch + coalesced epilogue ----
__global__ __launch_bounds__(256) void mfma_gemm_bf(const unsigned short* __restrict__ A,
                                                    const unsigned short* __restrict__ B,
                                                    float* __restrict__ C,
                                                    int M, int N, int K) {
    __shared__ __align__(16) unsigned short SMEM[2 * MB * LDT];
    unsigned short* As = SMEM;
    unsigned short* Bs = SMEM + MB * LDT;
    int tid = threadIdx.x;
    int nt_m = M / MB;
    int total = gridDim.x;
    int bid = blockIdx.x;
    int swz = bid;
    if ((total & 7) == 0) {
        int chunk = total >> 3;
        swz = (bid & 7) * chunk + (bid >> 3);
    }
    int bm = (swz % nt_m) * MB;
    int bn = (swz / nt_m) * NB;
    int srow = tid >> 1, shalf = tid & 1;
    int lane = tid & 63, w = tid >> 6;
    int wr = w >> 1, wc = w & 1;
    int r0 = (lane >> 4) * 4, c0 = lane & 15;
    int kb = (lane >> 4) * 8;

    bool bval = (bn + srow) < N;
    const unsigned short* Ap = A + (size_t)(bm + srow) * K + shalf * 16;
    const unsigned short* Bp = B + (size_t)(bn + srow) * K + shalf * 16;

    int nk = K / KB;
    uint4 ra0[2], ra1[2], rb0[2], rb1[2];
    #pragma unroll
    for (int s = 0; s < 2; ++s) {
        const uint4* pa = reinterpret_cast<const uint4*>(Ap + s * KB);
        ra0[s] = pa[0]; ra1[s] = pa[1];
        rb0[s] = make_uint4(0,0,0,0); rb1[s] = make_uint4(0,0,0,0);
        if (bval) {
            const uint4* pb = reinterpret_cast<const uint4*>(Bp + s * KB);
            rb0[s] = pb[0]; rb1[s] = pb[1];
        }
    }

    f32x4 acc[4][4] = {};

    for (int i = 0; i < nk; ++i) {
        int s = i & 1;
        uint4* da = reinterpret_cast<uint4*>(&As[srow * LDT + shalf * 16]);
        da[0] = ra0[s]; da[1] = ra1[s];
        uint4* db = reinterpret_cast<uint4*>(&Bs[srow * LDT + shalf * 16]);
        db[0] = rb0[s]; db[1] = rb1[s];
        __syncthreads();
        if (i + 2 < nk) {
            const uint4* pa = reinterpret_cast<const uint4*>(Ap + (i + 2) * KB);
            ra0[s] = pa[0]; ra1[s] = pa[1];
            if (bval) {
                const uint4* pb = reinterpret_cast<const uint4*>(Bp + (i + 2) * KB);
                rb0[s] = pb[0]; rb1[s] = pb[1];
            }
        }
        bf16x8 af[4], bf[4];
        #pragma unroll
        for (int m = 0; m < 4; ++m)
            af[m] = *reinterpret_cast<const bf16x8*>(&As[(wr * 64 + m * 16 + c0) * LDT + kb]);
        #pragma unroll
        for (int n = 0; n < 4; ++n)
            bf[n] = *reinterpret_cast<const bf16x8*>(&Bs[(wc * 64 + n * 16 + c0) * LDT + kb]);
        #pragma unroll
        for (int m = 0; m < 4; ++m)
            #pragma unroll
            for (int n = 0; n < 4; ++n)
                acc[m][n] = __builtin_amdgcn_mfma_f32_16x16x32_bf16(af[m], bf[n], acc[m][n], 0, 0, 0);
        __syncthreads();
    }

    float* Ct = reinterpret_cast<float*>(SMEM);
    float* cw = Ct + w * 1024;
    #pragma unroll
    for (int m = 0; m < 4; ++m) {
        #pragma unroll
        for (int n = 0; n < 4; ++n)
            #pragma unroll
            for (int r = 0; r < 4; ++r)
                cw[(r0 + r) * 64 + n * 16 + c0] = acc[m][n][r];
        #pragma unroll
        for (int ch = 0; ch < 4; ++ch) {
            f32x4 vv = *reinterpret_cast<const f32x4*>(&cw[ch * 256 + lane * 4]);
            int rg = bm + wr * 64 + m * 16 + ch * 4 + (lane >> 4);
            int cg = bn + wc * 64 + (lane & 15) * 4;
            if (cg + 3 < N) {
                *reinterpret_cast<f32x4*>(&C[(size_t)rg * N + cg]) = vv;
            } else {
                #pragma unroll
                for (int e = 0; e < 4; ++e)
                    if (cg + e < N) C[(size_t)rg * N + cg + e] = vv[e];
            }
        }
    }
}

// ---- Plain bf16 MFMA GEMM from fp32 (fallback logits path) ----
__global__ __launch_bounds__(256) void mfma_gemm(const float* __restrict__ A,
                                                 const float* __restrict__ B,
                                                 float* __restrict__ C,
                                                 int M, int N, int K) {
    __shared__ __align__(16) unsigned short As[MB * LDT];
    __shared__ __align__(16) unsigned short Bs[NB * LDT];
    int tid = threadIdx.x;
    int bm = blockIdx.y * MB, bn = blockIdx.x * NB;
    int srow = tid >> 1, shalf = tid & 1;
    int lane = tid & 63, w = tid >> 6;
    int wr = w >> 1, wc = w & 1;
    int r0 = (lane >> 4) * 4, c0 = lane & 15;
    int kb = (lane >> 4) * 8;

    f32x4 acc[4][4] = {};

    for (int kk = 0; kk < K; kk += KB) {
        stage_tile(As, A + (size_t)(bm + srow) * K + kk + shalf * 16, true, srow, shalf);
        bool bval = (bn + srow) < N;
        stage_tile(Bs, B + (size_t)(bn + srow) * K + kk + shalf * 16, bval, srow, shalf);
        __syncthreads();
        bf16x8 af[4], bf[4];
        #pragma unroll
        for (int m = 0; m < 4; ++m)
            af[m] = *reinterpret_cast<const bf16x8*>(&As[(wr * 64 + m * 16 + c0) * LDT + kb]);
        #pragma unroll
        for (int n = 0; n < 4; ++n)
            bf[n] = *reinterpret_cast<const bf16x8*>(&Bs[(wc * 64 + n * 16 + c0) * LDT + kb]);
        #pragma unroll
        for (int m = 0; m < 4; ++m)
            #pragma unroll
            for (int n = 0; n < 4; ++n)
                acc[m][n] = __builtin_amdgcn_mfma_f32_16x16x32_bf16(af[m], bf[n], acc[m][n], 0, 0, 0);
        __syncthreads();
    }

    #pragma unroll
    for (int n = 0; n < 4; ++n) {
        int col = bn + wc * 64 + n * 16 + c0;
        if (col < N) {
            #pragma unroll
            for (int m = 0; m < 4; ++m)
                #pragma unroll
                for (int r = 0; r < 4; ++r) {
                    int row = bm + wr * 64 + m * 16 + r0 + r;
                    C[(size_t)row * N + col] = acc[m][n][r];
                }
        }
    }
}

// ---- Split GEMM, pre-split A + fp32 B, K-SPLIT PARTIAL, register prefetch ----
__global__ __launch_bounds__(256) void mfma_gemm_pA_part(const unsigned short* __restrict__ Ahp,
                                                         const unsigned short* __restrict__ Alp,
                                                         const float* __restrict__ B,
                                                         float* __restrict__ part,
                                                         int M, int N, int K, int KSPLIT) {
    __shared__ __align__(16) unsigned short SMEM[4 * MB * LDT];
    unsigned short* Ah = SMEM;
    unsigned short* Al = SMEM + MB * LDT;
    unsigned short* Bh = SMEM + 2 * MB * LDT;
    unsigned short* Bl = SMEM + 3 * MB * LDT;
    int tid = threadIdx.x;
    int bm = blockIdx.y * MB, bn = blockIdx.x * NB;
    int kc = blockIdx.z;
    int chunk = K / KSPLIT;
    int kbeg = kc * chunk;
    int srow = tid >> 1, shalf = tid & 1;
    int lane = tid & 63, w = tid >> 6;
    int wr = w >> 1, wc = w & 1;
    int r0 = (lane >> 4) * 4, c0 = lane & 15;
    int kb = (lane >> 4) * 8;

    const unsigned short* ApH = Ahp + (size_t)(bm + srow) * K + shalf * 16;
    const unsigned short* ApL = Alp + (size_t)(bm + srow) * K + shalf * 16;
    const float* Bp = B + (size_t)(bn + srow) * K + shalf * 16;

    // preload first K-step
    uint4 rah0 = reinterpret_cast<const uint4*>(ApH + kbeg)[0];
    uint4 rah1 = reinterpret_cast<const uint4*>(ApH + kbeg)[1];
    uint4 ral0 = reinterpret_cast<const uint4*>(ApL + kbeg)[0];
    uint4 ral1 = reinterpret_cast<const uint4*>(ApL + kbeg)[1];
    float4 rbv[4];
    #pragma unroll
    for (int q = 0; q < 4; ++q)
        rbv[q] = reinterpret_cast<const float4*>(Bp + kbeg)[q];

    f32x4 acc[4][4] = {};

    for (int kk = kbeg; kk < kbeg + chunk; kk += KB) {
        uint4* dah = reinterpret_cast<uint4*>(&Ah[srow * LDT + shalf * 16]);
        dah[0] = rah0; dah[1] = rah1;
        uint4* dal = reinterpret_cast<uint4*>(&Al[srow * LDT + shalf * 16]);
        dal[0] = ral0; dal[1] = ral1;
        stage_split_regs(Bh, Bl, rbv, srow, shalf);
        __syncthreads();
        if (kk + KB < kbeg + chunk) {
            int kn = kk + KB;
            rah0 = reinterpret_cast<const uint4*>(ApH + kn)[0];
            rah1 = reinterpret_cast<const uint4*>(ApH + kn)[1];
            ral0 = reinterpret_cast<const uint4*>(ApL + kn)[0];
            ral1 = reinterpret_cast<const uint4*>(ApL + kn)[1];
            #pragma unroll
            for (int q = 0; q < 4; ++q)
                rbv[q] = reinterpret_cast<const float4*>(Bp + kn)[q];
        }
        bf16x8 ah[4], al[4], bh[4], bl[4];
        #pragma unroll
        for (int m = 0; m < 4; ++m) {
            int o = (wr * 64 + m * 16 + c0) * LDT + kb;
            ah[m] = *reinterpret_cast<const bf16x8*>(&Ah[o]);
            al[m] = *reinterpret_cast<const bf16x8*>(&Al[o]);
        }
        #pragma unroll
        for (int n = 0; n < 4; ++n) {
            int o = (wc * 64 + n * 16 + c0) * LDT + kb;
            bh[n] = *reinterpret_cast<const bf16x8*>(&Bh[o]);
            bl[n] = *reinterpret_cast<const bf16x8*>(&Bl[o]);
        }
        #pragma unroll
        for (int m = 0; m < 4; ++m)
            #pragma unroll
            for (int n = 0; n < 4; ++n) {
                acc[m][n] = __builtin_amdgcn_mfma_f32_16x16x32_bf16(al[m], bh[n], acc[m][n], 0, 0, 0);
                acc[m][n] = __builtin_amdgcn_mfma_f32_16x16x32_bf16(ah[m], bl[n], acc[m][n], 0, 0, 0);
                acc[m][n] = __builtin_amdgcn_mfma_f32_16x16x32_bf16(ah[m], bh[n], acc[m][n], 0, 0, 0);
            }
        __syncthreads();
    }

    float* Ct = reinterpret_cast<float*>(SMEM);
    float* cw = Ct + w * 1024;
    float* P = part + (size_t)kc * M * N;
    #pragma unroll
    for (int m = 0; m < 4; ++m) {
        #pragma unroll
        for (int n = 0; n < 4; ++n)
            #pragma unroll
            for (int r = 0; r < 4; ++r)
                cw[(r0 + r) * 64 + n * 16 + c0] = acc[m][n][r];
        #pragma unroll
        for (int ch = 0; ch < 4; ++ch) {
            f32x4 vv = *reinterpret_cast<const f32x4*>(&cw[ch * 256 + lane * 4]);
            int rg = bm + wr * 64 + m * 16 + ch * 4 + (lane >> 4);
            int cg = bn + wc * 64 + (lane & 15) * 4;
            *reinterpret_cast<f32x4*>(&P[(size_t)rg * N + cg]) = vv;
        }
    }
}

// ---- Dense reduce (fp32 out, no act): qkv ----
__global__ __launch_bounds__(256) void reduce_dense(const float* __restrict__ part,
                                                    const float* __restrict__ bias,
                                                    float* __restrict__ C,
                                                    long MN, int N, int KSPLIT) {
    long stride = (long)gridDim.x * 256 * 4;
    for (long i = ((long)blockIdx.x * 256 + threadIdx.x) * 4; i < MN; i += stride) {
        float4 v = *reinterpret_cast<const float4*>(part + i);
        for (int kc = 1; kc < KSPLIT; ++kc) {
            float4 p = *reinterpret_cast<const float4*>(part + (size_t)kc * MN + i);
            v.x += p.x; v.y += p.y; v.z += p.z; v.w += p.w;
        }
        int col = (int)(i % N);
        float4 b = *reinterpret_cast<const float4*>(bias + col);
        v.x += b.x; v.y += b.y; v.z += b.z; v.w += b.w;
        *reinterpret_cast<float4*>(C + i) = v;
    }
}

// ---- FFN1 reduce: gelu(Σ parts + bias) -> hi/lo bf16 ----
__global__ __launch_bounds__(256) void reduce_gelu_bf(const float* __restrict__ part,
                                                      const float* __restrict__ bias,
                                                      unsigned short* __restrict__ outh,
                                                      unsigned short* __restrict__ outl,
                                                      long MN, int N, int KSPLIT) {
    long stride = (long)gridDim.x * 256 * 4;
    for (long i = ((long)blockIdx.x * 256 + threadIdx.x) * 4; i < MN; i += stride) {
        float4 v = *reinterpret_cast<const float4*>(part + i);
        for (int kc = 1; kc < KSPLIT; ++kc) {
            float4 p = *reinterpret_cast<const float4*>(part + (size_t)kc * MN + i);
            v.x += p.x; v.y += p.y; v.z += p.z; v.w += p.w;
        }
        int col = (int)(i % N);
        float4 b = *reinterpret_cast<const float4*>(bias + col);
        float f[4];
        f[0] = gelu_exact(v.x + b.x); f[1] = gelu_exact(v.y + b.y);
        f[2] = gelu_exact(v.z + b.z); f[3] = gelu_exact(v.w + b.w);
        union { unsigned short s[4]; uint2 u; } ph, pl;
        #pragma unroll
        for (int e = 0; e < 4; ++e) {
            unsigned short hb = f2bf(f[e]);
            ph.s[e] = hb;
            pl.s[e] = f2bf(f[e] - bf2f_bits(hb));
        }
        *reinterpret_cast<uint2*>(outh + i) = ph.u;
        *reinterpret_cast<uint2*>(outl + i) = pl.u;
    }
}

// ---- Fused reduce(+bias+res into h) + LN -> xn (fp32) + xn hi/lo ----
__global__ __launch_bounds__(256) void reduce_ln(const float* __restrict__ part,
                                                 const float* __restrict__ bias,
                                                 float* __restrict__ h,
                                                 const float* __restrict__ g,
                                                 const float* __restrict__ b,
                                                 float* __restrict__ xn,
                                                 unsigned short* __restrict__ xnh,
                                                 unsigned short* __restrict__ xnl,
                                                 int KSPLIT) {
    const long MN = (long)NT * Dm;
    int t = blockIdx.x, tid = threadIdx.x;
    float v[3];
    #pragma unroll
    for (int j = 0; j < 3; ++j) {
        int col = tid + j * 256;
        long idx = (long)t * Dm + col;
        float s = part[idx];
        for (int kc = 1; kc < KSPLIT; ++kc) s += part[(size_t)kc * MN + idx];
        s += bias[col] + h[idx];
        h[idx] = s;
        v[j] = s;
    }
    __shared__ float red[256];
    red[tid] = v[0] + v[1] + v[2];
    __syncthreads();
    for (int off = 128; off > 0; off >>= 1) {
        if (tid < off) red[tid] += red[tid + off];
        __syncthreads();
    }
    float mean = red[0] * (1.0f / Dm);
    __syncthreads();
    float d0 = v[0] - mean, d1 = v[1] - mean, d2 = v[2] - mean;
    red[tid] = d0 * d0 + d1 * d1 + d2 * d2;
    __syncthreads();
    for (int off = 128; off > 0; off >>= 1) {
        if (tid < off) red[tid] += red[tid + off];
        __syncthreads();
    }
    float inv = rsqrtf(red[0] * (1.0f / Dm) + 1e-5f);
    float o0 = d0 * inv * g[tid]       + b[tid];
    float o1 = d1 * inv * g[tid + 256] + b[tid + 256];
    float o2 = d2 * inv * g[tid + 512] + b[tid + 512];
    long base = (size_t)t * Dm;
    xn[base + tid] = o0; xn[base + tid + 256] = o1; xn[base + tid + 512] = o2;
    unsigned short h0 = f2bf(o0), h1 = f2bf(o1), h2 = f2bf(o2);
    xnh[base + tid] = h0; xnh[base + tid + 256] = h1; xnh[base + tid + 512] = h2;
    xnl[base + tid]       = f2bf(o0 - bf2f_bits(h0));
    xnl[base + tid + 256] = f2bf(o1 - bf2f_bits(h1));
    xnl[base + tid + 512] = f2bf(o2 - bf2f_bits(h2));
}

// ---- Fused MoE combine + LN -> xn + hi/lo ----
__global__ __launch_bounds__(256) void combine_ln(float* __restrict__ h,
                                                  const float* __restrict__ ye,
                                                  const float* __restrict__ g,
                                                  const float* __restrict__ b,
                                                  float* __restrict__ xn,
                                                  unsigned short* __restrict__ xnh,
                                                  unsigned short* __restrict__ xnl) {
    int t = blockIdx.x, tid = threadIdx.x;
    float v[3];
    #pragma unroll
    for (int j = 0; j < 3; ++j) {
        int col = tid + j * 256;
        long idx = (long)t * Dm + col;
        float s = h[idx] + ye[(size_t)(t * 2) * Dm + col] + ye[(size_t)(t * 2 + 1) * Dm + col];
        h[idx] = s;
        v[j] = s;
    }
    __shared__ float red[256];
    red[tid] = v[0] + v[1] + v[2];
    __syncthreads();
    for (int off = 128; off > 0; off >>= 1) {
        if (tid < off) red[tid] += red[tid + off];
        __syncthreads();
    }
    float mean = red[0] * (1.0f / Dm);
    __syncthreads();
    float d0 = v[0] - mean, d1 = v[1] - mean, d2 = v[2] - mean;
    red[tid] = d0 * d0 + d1 * d1 + d2 * d2;
    __syncthreads();
    for (int off = 128; off > 0; off >>= 1) {
        if (tid < off) red[tid] += red[tid + off];
        __syncthreads();
    }
    float inv = rsqrtf(red[0] * (1.0f / Dm) + 1e-5f);
    float o0 = d0 * inv * g[tid]       + b[tid];
    float o1 = d1 * inv * g[tid + 256] + b[tid + 256];
    float o2 = d2 * inv * g[tid + 512] + b[tid + 512];
    long base = (size_t)t * Dm;
    xn[base + tid] = o0; xn[base + tid + 256] = o1; xn[base + tid + 512] = o2;
    unsigned short h0 = f2bf(o0), h1 = f2bf(o1), h2 = f2bf(o2);
    xnh[base + tid] = h0; xnh[base + tid + 256] = h1; xnh[base + tid + 512] = h2;
    xnl[base + tid]       = f2bf(o0 - bf2f_bits(h0));
    xnl[base + tid + 256] = f2bf(o1 - bf2f_bits(h1));
    xnl[base + tid + 512] = f2bf(o2 - bf2f_bits(h2));
}

// ---------------- Flash attention, split-bf16 MFMA; outputs hi/lo bf16 ----------------
#define LDA 72
__device__ __forceinline__ void stage16a(unsigned short* dh, unsigned short* dl,
                                         const float* src) {
    union { unsigned short s[8]; uint4 v; } h0, h1, l0, l1;
    const float4* s4 = reinterpret_cast<const float4*>(src);
    #pragma unroll
    for (int q = 0; q < 4; ++q) {
        float4 f = s4[q];
        float vv[4] = {f.x, f.y, f.z, f.w};
        #pragma unroll
        for (int j = 0; j < 4; ++j) {
            int idx = q * 4 + j;
            unsigned short hb = f2bf(vv[j]);
            unsigned short lb = f2bf(vv[j] - bf2f_bits(hb));
            if (idx < 8) { h0.s[idx] = hb; l0.s[idx] = lb; }
            else         { h1.s[idx - 8] = hb; l1.s[idx - 8] = lb; }
        }
    }
    reinterpret_cast<uint4*>(dh)[0] = h0.v; reinterpret_cast<uint4*>(dh)[1] = h1.v;
    reinterpret_cast<uint4*>(dl)[0] = l0.v; reinterpret_cast<uint4*>(dl)[1] = l1.v;
}

__global__ __launch_bounds__(256) void attn_flash(const float* __restrict__ qkv,
                                                  unsigned short* __restrict__ aoh,
                                                  unsigned short* __restrict__ aol) {
    int qt = blockIdx.x;
    int bh = blockIdx.y;
    int b = bh / NHm, hh = bh % NHm;
    const int g0 = b * Tm;
    const int hoff = hh * 64;
    int tid = threadIdx.x;
    int lane = tid & 63, w = tid >> 6;
    int c0 = lane & 15, hi4 = lane >> 4;
    int kb = hi4 * 8;

    __shared__ __align__(16) unsigned short Qh[64 * LDA], Ql[64 * LDA];
    __shared__ __align__(16) unsigned short Kh[64 * LDA], Kl[64 * LDA];
    __shared__ __align__(16) unsigned short Vh[64 * LDA], Vl[64 * LDA];
    __shared__ __align__(16) unsigned short Ph[4][16 * LDA], Pl[4][16 * LDA];

    {
        int srow = tid >> 2, q = tid & 3;
        stage16a(&Qh[srow * LDA + q * 16], &Ql[srow * LDA + q * 16],
                 qkv + (size_t)(g0 + qt * 64 + srow) * (3 * Dm) + hoff + q * 16);
    }
    __syncthreads();

    f32x4 acc_o[4] = {};
    float m_r[4] = {-1e30f, -1e30f, -1e30f, -1e30f};
    float l_r[4] = {0.f, 0.f, 0.f, 0.f};

    for (int kt = 0; kt <= qt; ++kt) {
        {
            int srow = tid >> 2, q = tid & 3;
            stage16a(&Kh[srow * LDA + q * 16], &Kl[srow * LDA + q * 16],
                     qkv + (size_t)(g0 + kt * 64 + srow) * (3 * Dm) + Dm + hoff + q * 16);
        }
        {
            int d = lane, kg = w;
            const float* vbase = qkv + (size_t)(g0 + kt * 64 + kg * 16) * (3 * Dm) + 2 * Dm + hoff + d;
            #pragma unroll
            for (int k2 = 0; k2 < 16; ++k2) {
                float v = vbase[(size_t)k2 * (3 * Dm)];
                unsigned short hb = f2bf(v);
                Vh[d * LDA + kg * 16 + k2] = hb;
                Vl[d * LDA + kg * 16 + k2] = f2bf(v - bf2f_bits(hb));
            }
        }
        __syncthreads();

        f32x4 sAcc[4] = {};
        #pragma unroll
        for (int kk2 = 0; kk2 < 64; kk2 += 32) {
            bf16x8 ah = *reinterpret_cast<const bf16x8*>(&Qh[(w * 16 + c0) * LDA + kk2 + kb]);
            bf16x8 al = *reinterpret_cast<const bf16x8*>(&Ql[(w * 16 + c0) * LDA + kk2 + kb]);
            #pragma unroll
            for (int n = 0; n < 4; ++n) {
                bf16x8 bh_ = *reinterpret_cast<const bf16x8*>(&Kh[(n * 16 + c0) * LDA + kk2 + kb]);
                bf16x8 bl_ = *reinterpret_cast<const bf16x8*>(&Kl[(n * 16 + c0) * LDA + kk2 + kb]);
                sAcc[n] = __builtin_amdgcn_mfma_f32_16x16x32_bf16(al, bh_, sAcc[n], 0, 0, 0);
                sAcc[n] = __builtin_amdgcn_mfma_f32_16x16x32_bf16(ah, bl_, sAcc[n], 0, 0, 0);
                sAcc[n] = __builtin_amdgcn_mfma_f32_16x16x32_bf16(ah, bh_, sAcc[n], 0, 0, 0);
            }
        }

        float p[4][4];
        float smax[4] = {-3e38f, -3e38f, -3e38f, -3e38f};
        #pragma unroll
        for (int n = 0; n < 4; ++n)
            #pragma unroll
            for (int r = 0; r < 4; ++r) {
                float s = sAcc[n][r] * 0.125f;
                if (kt == qt) {
                    int kg = n * 16 + c0;
                    int qg = w * 16 + hi4 * 4 + r;
                    if (kg > qg) s = -3e38f;
                }
                p[n][r] = s;
                smax[r] = fmaxf(smax[r], s);
            }
        #pragma unroll
        for (int off = 1; off < 16; off <<= 1)
            #pragma unroll
            for (int r = 0; r < 4; ++r)
                smax[r] = fmaxf(smax[r], __shfl_xor(smax[r], off));
        float f_r[4], lsum[4];
        #pragma unroll
        for (int r = 0; r < 4; ++r) {
            float mn = fmaxf(m_r[r], smax[r]);
            f_r[r] = expf(m_r[r] - mn);
            m_r[r] = mn;
        }
        #pragma unroll
        for (int n = 0; n < 4; ++n)
            #pragma unroll
            for (int r = 0; r < 4; ++r)
                p[n][r] = expf(p[n][r] - m_r[r]);
        #pragma unroll
        for (int r = 0; r < 4; ++r)
            lsum[r] = p[0][r] + p[1][r] + p[2][r] + p[3][r];
        #pragma unroll
        for (int off = 1; off < 16; off <<= 1)
            #pragma unroll
            for (int r = 0; r < 4; ++r)
                lsum[r] += __shfl_xor(lsum[r], off);
        #pragma unroll
        for (int r = 0; r < 4; ++r)
            l_r[r] = l_r[r] * f_r[r] + lsum[r];
        #pragma unroll
        for (int n = 0; n < 4; ++n)
            #pragma unroll
            for (int r = 0; r < 4; ++r)
                acc_o[n][r] *= f_r[r];

        #pragma unroll
        for (int n = 0; n < 4; ++n)
            #pragma unroll
            for (int r = 0; r < 4; ++r) {
                unsigned short hb = f2bf(p[n][r]);
                int o = (hi4 * 4 + r) * LDA + n * 16 + c0;
                Ph[w][o] = hb;
                Pl[w][o] = f2bf(p[n][r] - bf2f_bits(hb));
            }

        #pragma unroll
        for (int kk2 = 0; kk2 < 64; kk2 += 32) {
            bf16x8 pah = *reinterpret_cast<const bf16x8*>(&Ph[w][c0 * LDA + kk2 + kb]);
            bf16x8 pal = *reinterpret_cast<const bf16x8*>(&Pl[w][c0 * LDA + kk2 + kb]);
            #pragma unroll
            for (int n = 0; n < 4; ++n) {
                bf16x8 vbh = *reinterpret_cast<const bf16x8*>(&Vh[(n * 16 + c0) * LDA + kk2 + kb]);
                bf16x8 vbl = *reinterpret_cast<const bf16x8*>(&Vl[(n * 16 + c0) * LDA + kk2 + kb]);
                acc_o[n] = __builtin_amdgcn_mfma_f32_16x16x32_bf16(pal, vbh, acc_o[n], 0, 0, 0);
                acc_o[n] = __builtin_amdgcn_mfma_f32_16x16x32_bf16(pah, vbl, acc_o[n], 0, 0, 0);
                acc_o[n] = __builtin_amdgcn_mfma_f32_16x16x32_bf16(pah, vbh, acc_o[n], 0, 0, 0);
            }
        }
        __syncthreads();
    }

    float inv[4];
    #pragma unroll
    for (int r = 0; r < 4; ++r) inv[r] = 1.0f / l_r[r];
    #pragma unroll
    for (int n = 0; n < 4; ++n)
        #pragma unroll
        for (int r = 0; r < 4; ++r) {
            int row = g0 + qt * 64 + w * 16 + hi4 * 4 + r;
            float v = acc_o[n][r] * inv[r];
            unsigned short hb = f2bf(v);
            size_t idx = (size_t)row * Dm + hoff + n * 16 + c0;
            aoh[idx] = hb;
            aol[idx] = f2bf(v - bf2f_bits(hb));
        }
}

// ---------------- MoE router: wave-parallel (fp32 xn) ----------------
__global__ __launch_bounds__(256) void router_kernel(const float* __restrict__ xn,
                                                     const float* __restrict__ gw,
                                                     int* __restrict__ topi,
                                                     float* __restrict__ topw) {
    int t = blockIdx.x * 4 + (threadIdx.x >> 6);
    int lane = threadIdx.x & 63;
    const float4* x4 = reinterpret_cast<const float4*>(xn + (size_t)t * Dm);
    float4 xv[3];
    #pragma unroll
    for (int i = 0; i < 3; ++i) xv[i] = x4[lane + i * 64];

    float l[Em];
    #pragma unroll
    for (int e = 0; e < Em; ++e) {
        const float4* w4 = reinterpret_cast<const float4*>(gw + (size_t)e * Dm);
        float dot = 0.f;
        #pragma unroll
        for (int i = 0; i < 3; ++i) {
            float4 wv = w4[lane + i * 64];
            dot += xv[i].x * wv.x + xv[i].y * wv.y + xv[i].z * wv.z + xv[i].w * wv.w;
        }
        #pragma unroll
        for (int off = 32; off > 0; off >>= 1) dot += __shfl_xor(dot, off);
        l[e] = dot;
    }
    if (lane == 0) {
        int i1 = 0;
        #pragma unroll
        for (int e = 1; e < Em; ++e) if (l[e] > l[i1]) i1 = e;
        int i2 = (i1 == 0) ? 1 : 0;
        #pragma unroll
        for (int e = 0; e < Em; ++e) if (e != i1 && l[e] > l[i2]) i2 = e;
        float w1 = 1.0f / (1.0f + expf(l[i2] - l[i1]));
        topi[t * 2] = i1; topi[t * 2 + 1] = i2;
        topw[t * 2] = w1; topw[t * 2 + 1] = 1.0f - w1;
    }
}

// ---------------- Route build ----------------
__global__ __launch_bounds__(256) void route_build_kernel(const int* __restrict__ topi,
                                                          int* __restrict__ g_cnt,
                                                          int* __restrict__ g_off,
                                                          int* __restrict__ bucket) {
    __shared__ int cnt[Em], off[Em], pos[Em];
    int tid = threadIdx.x;
    if (tid < Em) cnt[tid] = 0;
    __syncthreads();
    for (int ts = tid; ts < NAS; ts += 256) atomicAdd(&cnt[topi[ts]], 1);
    __syncthreads();
    if (tid == 0) {
        int acc = 0;
        for (int e = 0; e < Em; ++e) { off[e] = acc; pos[e] = acc; acc += cnt[e]; }
    }
    __syncthreads();
    for (int ts = tid; ts < NAS; ts += 256) {
        int e = topi[ts];
        int p = atomicAdd(&pos[e], 1);
        bucket[p] = ts;
    }
    if (tid < Em) { g_cnt[tid] = cnt[tid]; g_off[tid] = off[tid]; }
}

// ---------------- Grouped MoE GEMM1: A = xn hi/lo, B = fp32 weights; out heg hi/lo ----
template<int SPLIT>
__global__ __launch_bounds__(256) void moe_mfma_gemm1(const unsigned short* __restrict__ xnh,
                                                      const unsigned short* __restrict__ xnl,
                                                      const float* __restrict__ W1all,
                                                      const float* __restrict__ B1all,
                                                      const int* __restrict__ bucket,
                                                      const int* __restrict__ cnt,
                                                      const int* __restrict__ off,
                                                      unsigned short* __restrict__ hegh,
                                                      unsigned short* __restrict__ hegl) {
    int e = blockIdx.z;
    int count = cnt[e];
    int mbase = blockIdx.y * MB;
    if (mbase >= count) return;
    int base = off[e];

    __shared__ __align__(16) unsigned short Ah[MB * LDT];
    __shared__ __align__(16) unsigned short Bh[NB * LDT];
    __shared__ __align__(16) unsigned short Al[SPLIT ? MB * LDT : 8];
    __shared__ __align__(16) unsigned short Bl[SPLIT ? NB * LDT : 8];
    __shared__ int toks[MB];
    int tid = threadIdx.x;
    int bn = blockIdx.x * NB;
    int srow = tid >> 1, shalf = tid & 1;
    int lane = tid & 63, w = tid >> 6;
    int wr = w >> 1, wc = w & 1;
    int r0 = (lane >> 4) * 4, c0 = lane & 15;
    int kb = (lane >> 4) * 8;
    if (tid < MB) {
        int p = mbase + tid;
        toks[tid] = (p < count) ? (bucket[base + p] >> 1) : -1;
    }
    __syncthreads();

    f32x4 acc[4][4] = {};
    const float* W = W1all + (size_t)e * Hm * Dm;
    int t = toks[srow];
    for (int kk = 0; kk < Dm; kk += KB) {
        size_t aoff = (size_t)t * Dm + kk + shalf * 16;
        stage_tile_copy(Ah, xnh + aoff, t >= 0, srow, shalf);
        if (SPLIT) {
            stage_tile_copy(Al, xnl + aoff, t >= 0, srow, shalf);
            stage_tile_split(Bh, Bl, W + (size_t)(bn + srow) * Dm + kk + shalf * 16, true, srow, shalf);
        } else {
            stage_tile(Bh, W + (size_t)(bn + srow) * Dm + kk + shalf * 16, true, srow, shalf);
        }
        __syncthreads();
        bf16x8 ah[4], bh[4], al[4], bl[4];
        #pragma unroll
        for (int m = 0; m < 4; ++m) {
            int o = (wr * 64 + m * 16 + c0) * LDT + kb;
            ah[m] = *reinterpret_cast<const bf16x8*>(&Ah[o]);
            if (SPLIT) al[m] = *reinterpret_cast<const bf16x8*>(&Al[o]);
        }
        #pragma unroll
        for (int n = 0; n < 4; ++n) {
            int o = (wc * 64 + n * 16 + c0) * LDT + kb;
            bh[n] = *reinterpret_cast<const bf16x8*>(&Bh[o]);
            if (SPLIT) bl[n] = *reinterpret_cast<const bf16x8*>(&Bl[o]);
        }
        #pragma unroll
        for (int m = 0; m < 4; ++m)
            #pragma unroll
            for (int n = 0; n < 4; ++n) {
                if (SPLIT) {
                    acc[m][n] = __builtin_amdgcn_mfma_f32_16x16x32_bf16(al[m], bh[n], acc[m][n], 0, 0, 0);
                    acc[m][n] = __builtin_amdgcn_mfma_f32_16x16x32_bf16(ah[m], bl[n], acc[m][n], 0, 0, 0);
                }
                acc[m][n] = __builtin_amdgcn_mfma_f32_16x16x32_bf16(ah[m], bh[n], acc[m][n], 0, 0, 0);
            }
        __syncthreads();
    }

    const float* b1 = B1all + (size_t)e * Hm;
    #pragma unroll
    for (int n = 0; n < 4; ++n) {
        int col = bn + wc * 64 + n * 16 + c0;
        float bv = b1[col];
        #pragma unroll
        for (int m = 0; m < 4; ++m) {
            #pragma unroll
            for (int r = 0; r < 4; ++r) {
                int p = mbase + wr * 64 + m * 16 + r0 + r;
                if (p < count) {
                    float v = gelu_exact(acc[m][n][r] + bv);
                    unsigned short hb = f2bf(v);
                    size_t idx = (size_t)(base + p) * Hm + col;
                    hegh[idx] = hb;
                    hegl[idx] = f2bf(v - bf2f_bits(hb));
                }
            }
        }
    }
}

// ---------------- Grouped MoE GEMM2: A = heg hi/lo, B = fp32; K-SPLIT partial ----
template<int SPLIT>
__global__ __launch_bounds__(256) void moe_gemm2_part(const unsigned short* __restrict__ hegh,
                                                      const unsigned short* __restrict__ hegl,
                                                      const float* __restrict__ W2all,
                                                      const int* __restrict__ cnt,
                                                      const int* __restrict__ off,
                                                      float* __restrict__ part,
                                                      int KSPLIT) {
    int e = blockIdx.z;
    int count = cnt[e];
    int my = blockIdx.y;
    int kc = my % KSPLIT, mb = my / KSPLIT;
    int mbase = mb * MB;
    if (mbase >= count) return;
    int base = off[e];
    int chunk = Hm / KSPLIT;
    int kbeg = kc * chunk;

    __shared__ __align__(16) unsigned short Ah[MB * LDT];
    __shared__ __align__(16) unsigned short Bh[NB * LDT];
    __shared__ __align__(16) unsigned short Al[SPLIT ? MB * LDT : 8];
    __shared__ __align__(16) unsigned short Bl[SPLIT ? NB * LDT : 8];
    int tid = threadIdx.x;
    int bn = blockIdx.x * NB;
    int srow = tid >> 1, shalf = tid & 1;
    int lane = tid & 63, w = tid >> 6;
    int wr = w >> 1, wc = w & 1;
    int r0 = (lane >> 4) * 4, c0 = lane & 15;
    int kb = (lane >> 4) * 8;

    f32x4 acc[4][4] = {};
    const float* W = W2all + (size_t)e * Dm * Hm;
    bool aval = (mbase + srow) < count;
    for (int kk = kbeg; kk < kbeg + chunk; kk += KB) {
        size_t aoff = (size_t)(base + mbase + srow) * Hm + kk + shalf * 16;
        stage_tile_copy(Ah, hegh + aoff, aval, srow, shalf);
        if (SPLIT) {
            stage_tile_copy(Al, hegl + aoff, aval, srow, shalf);
            stage_tile_split(Bh, Bl, W + (size_t)(bn + srow) * Hm + kk + shalf * 16, true, srow, shalf);
        } else {
            stage_tile(Bh, W + (size_t)(bn + srow) * Hm + kk + shalf * 16, true, srow, shalf);
        }
        __syncthreads();
        bf16x8 ah[4], bh[4], al[4], bl[4];
        #pragma unroll
        for (int m = 0; m < 4; ++m) {
            int o = (wr * 64 + m * 16 + c0) * LDT + kb;
            ah[m] = *reinterpret_cast<const bf16x8*>(&Ah[o]);
            if (SPLIT) al[m] = *reinterpret_cast<const bf16x8*>(&Al[o]);
        }
        #pragma unroll
        for (int n = 0; n < 4; ++n) {
            int o = (wc * 64 + n * 16 + c0) * LDT + kb;
            bh[n] = *reinterpret_cast<const bf16x8*>(&Bh[o]);
            if (SPLIT) bl[n] = *reinterpret_cast<const bf16x8*>(&Bl[o]);
        }
        #pragma unroll
        for (int m = 0; m < 4; ++m)
            #pragma unroll
            for (int n = 0; n < 4; ++n) {
                if (SPLIT) {
                    acc[m][n] = __builtin_amdgcn_mfma_f32_16x16x32_bf16(al[m], bh[n], acc[m][n], 0, 0, 0);
                    acc[m][n] = __builtin_amdgcn_mfma_f32_16x16x32_bf16(ah[m], bl[n], acc[m][n], 0, 0, 0);
                }
                acc[m][n] = __builtin_amdgcn_mfma_f32_16x16x32_bf16(ah[m], bh[n], acc[m][n], 0, 0, 0);
            }
        __syncthreads();
    }

    float* P = part + (size_t)kc * NAS * Dm;
    #pragma unroll
    for (int n = 0; n < 4; ++n) {
        int col = bn + wc * 64 + n * 16 + c0;
        #pragma unroll
        for (int m = 0; m < 4; ++m) {
            #pragma unroll
            for (int r = 0; r < 4; ++r) {
                int p = mbase + wr * 64 + m * 16 + r0 + r;
                if (p < count)
                    P[(size_t)(base + p) * Dm + col] = acc[m][n][r];
            }
        }
    }
}

// ---- MoE reduce: ye[ts] = topw[ts] * (Σ parts + b2[e]) ----
__global__ __launch_bounds__(256) void moe_reduce(const float* __restrict__ part,
                                                  const float* __restrict__ B2all,
                                                  const int* __restrict__ bucket,
                                                  const int* __restrict__ topi,
                                                  const float* __restrict__ topw,
                                                  float* __restrict__ ye, int KSPLIT) {
    const long MN = (long)NAS * Dm;
    long stride = (long)gridDim.x * 256 * 4;
    for (long i = ((long)blockIdx.x * 256 + threadIdx.x) * 4; i < MN; i += stride) {
        int p = (int)(i / Dm), col = (int)(i % Dm);
        int ts = bucket[p];
        int e = topi[ts];
        float wgt = topw[ts];
        float4 v = *reinterpret_cast<const float4*>(part + i);
        for (int kc = 1; kc < KSPLIT; ++kc) {
            float4 q = *reinterpret_cast<const float4*>(part + (size_t)kc * MN + i);
            v.x += q.x; v.y += q.y; v.z += q.z; v.w += q.w;
        }
        float4 b = *reinterpret_cast<const float4*>(B2all + (size_t)e * Dm + col);
        float4 o;
        o.x = wgt * (v.x + b.x); o.y = wgt * (v.y + b.y);
        o.z = wgt * (v.z + b.z); o.w = wgt * (v.w + b.w);
        *reinterpret_cast<float4*>(ye + (size_t)ts * Dm + col) = o;
    }
}

// ---------------- Launch ----------------
extern "C" void kernel_launch(void* const* d_in, const int* in_sizes, int n_in,
                              void* d_out, int out_size, void* d_ws, size_t ws_size,
                              hipStream_t stream) {
    const int*   x    = (const int*)d_in[0];
    const float* emb  = (const float*)d_in[1];
    const float* wqkv = (const float*)d_in[2];
    const float* bqkv = (const float*)d_in[3];
    const float* wo   = (const float*)d_in[4];
    const float* bo   = (const float*)d_in[5];
    const float* ln1g = (const float*)d_in[6];
    const float* ln1b = (const float*)d_in[7];
    const float* ln2g = (const float*)d_in[8];
    const float* ln2b = (const float*)d_in[9];
    const float* sw1  = (const float*)d_in[10];
    const float* sb1  = (const float*)d_in[11];
    const float* sw2  = (const float*)d_in[12];
    const float* sb2  = (const float*)d_in[13];
    const float* gw   = (const float*)d_in[14];
    const float* mw1  = (const float*)d_in[15];
    const float* mb1  = (const float*)d_in[16];
    const float* mw2  = (const float*)d_in[17];
    const float* mb2  = (const float*)d_in[18];
    const float* lnfg = (const float*)d_in[19];
    const float* lnfb = (const float*)d_in[20];

    const size_t n_h    = (size_t)NT * Dm;
    const size_t n_qkv  = (size_t)NT * 3 * Dm;
    const size_t n_ye   = (size_t)NAS * Dm;
    const size_t n_part = (size_t)NT * Hm * 2;
    const size_t n_xnb  = (size_t)NT * Dm / 2;
    const size_t n_ffhb = (size_t)NT * Hm / 2;
    const size_t n_hegb = (size_t)NAS * Hm / 2;
    const size_t n_embbf = (size_t)Vm * Dm / 2;
    const size_t n_big = n_h + n_qkv + n_ye + n_part
                       + 2 * n_xnb + 2 * n_xnb
                       + 2 * n_ffhb + 2 * n_hegb;

    size_t wsf = ws_size / sizeof(float);

    float* w = (float*)d_ws;
    float* xn   = w;            w += (size_t)NT * Dm;
    float* topw = w;            w += NAS;
    int*   topi = (int*)w;      w += NAS;
    int*   bucket = (int*)w;    w += NAS;
    int*   e_cnt = (int*)w;     w += 8;
    int*   e_off = (int*)w;     w += 8;
    size_t used = (size_t)(w - (float*)d_ws);

    unsigned short* emb_bf = nullptr;
    if (wsf >= used + n_embbf + 64) {
        emb_bf = (unsigned short*)w;  w += n_embbf;
        used = (size_t)(w - (float*)d_ws);
    }

    float *h, *qkv, *ye, *part;
    unsigned short *xnh, *xnl, *aoh, *aol, *ffhh, *ffhl, *hegh, *hegl;
    float* a;
    bool arena_in_out;
    if (wsf >= used + n_big + 64) { a = w; arena_in_out = false; }
    else                          { a = (float*)d_out; arena_in_out = true; }
    h = a;      a += n_h;
    qkv = a;    a += n_qkv;
    ye = a;     a += n_ye;
    part = a;   a += n_part;
    xnh = (unsigned short*)a;  a += n_xnb;
    xnl = (unsigned short*)a;  a += n_xnb;
    aoh = (unsigned short*)a;  a += n_xnb;
    aol = (unsigned short*)a;  a += n_xnb;
    ffhh = (unsigned short*)a; a += n_ffhb;
    ffhl = (unsigned short*)a; a += n_ffhb;
    hegh = (unsigned short*)a; a += n_hegb;
    hegl = (unsigned short*)a; a += n_hegb;

    if (emb_bf) {
        long n = (long)Vm * Dm;
        cvt_bf16_kernel<<<(unsigned)((n / 8 + 255) / 256), 256, 0, stream>>>(emb, emb_bf, n);
    }

    embed_kernel<<<NT, 256, 0, stream>>>(x, emb, h);
    ln_kernel<<<NT, 256, 0, stream>>>(h, ln1g, ln1b, xn, xnh, xnl);

    const int RBLK = 2048;
    int std_i = 0, moe_i = 0;
    for (int l = 0; l < Lm; ++l) {
        const float* ng = (l < 3) ? (ln1g + (l + 1) * Dm) : lnfg;
        const float* nb = (l < 3) ? (ln1b + (l + 1) * Dm) : lnfb;

        mfma_gemm_pA_part<<<dim3((3 * Dm) / NB, NT / MB, 2), 256, 0, stream>>>(
            xnh, xnl, wqkv + (size_t)l * 3 * Dm * Dm, part, NT, 3 * Dm, Dm, 2);
        reduce_dense<<<RBLK, 256, 0, stream>>>(
            part, bqkv + (size_t)l * 3 * Dm, qkv, (long)NT * 3 * Dm, 3 * Dm, 2);
        attn_flash<<<dim3(Tm / 64, Bm * NHm), 256, 0, stream>>>(qkv, aoh, aol);
        mfma_gemm_pA_part<<<dim3(Dm / NB, NT / MB, 4), 256, 0, stream>>>(
            aoh, aol, wo + (size_t)l * Dm * Dm, part, NT, Dm, Dm, 4);
        reduce_ln<<<NT, 256, 0, stream>>>(
            part, bo + (size_t)l * Dm, h, ln2g + l * Dm, ln2b + l * Dm, xn, xnh, xnl, 4);

        if (l == 1 || l == 3) {
            router_kernel<<<NT / 4, 256, 0, stream>>>(
                xn, gw + (size_t)moe_i * Em * Dm, topi, topw);
            route_build_kernel<<<1, 256, 0, stream>>>(topi, e_cnt, e_off, bucket);
            if (l == 3) {
                moe_mfma_gemm1<0><<<dim3(Hm / NB, NAS / MB, Em), 256, 0, stream>>>(
                    xnh, xnl, mw1 + (size_t)moe_i * Em * Hm * Dm, mb1 + (size_t)moe_i * Em * Hm,
                    bucket, e_cnt, e_off, hegh, hegl);
                moe_gemm2_part<0><<<dim3(Dm / NB, (NAS / MB) * 4, Em), 256, 0, stream>>>(
                    hegh, hegl, mw2 + (size_t)moe_i * Em * Dm * Hm, e_cnt, e_off, part, 4);
            } else {
                moe_mfma_gemm1<1><<<dim3(Hm / NB, NAS / MB, Em), 256, 0, stream>>>(
                    xnh, xnl, mw1 + (size_t)moe_i * Em * Hm * Dm, mb1 + (size_t)moe_i * Em * Hm,
                    bucket, e_cnt, e_off, hegh, hegl);
                moe_gemm2_part<1><<<dim3(Dm / NB, (NAS / MB) * 4, Em), 256, 0, stream>>>(
                    hegh, hegl, mw2 + (size_t)moe_i * Em * Dm * Hm, e_cnt, e_off, part, 4);
            }
            moe_reduce<<<RBLK, 256, 0, stream>>>(
                part, mb2 + (size_t)moe_i * Em * Dm, bucket, topi, topw, ye, 4);
            combine_ln<<<NT, 256, 0, stream>>>(h, ye, ng, nb, xn, xnh, xnl);
            moe_i++;
        } else {
            mfma_gemm_pA_part<<<dim3(Hm / NB, NT / MB, 2), 256, 0, stream>>>(
                xnh, xnl, sw1 + (size_t)std_i * Hm * Dm, part, NT, Hm, Dm, 2);
            reduce_gelu_bf<<<RBLK, 256, 0, stream>>>(
                part, sb1 + (size_t)std_i * Hm, ffhh, ffhl, (long)NT * Hm, Hm, 2);
            mfma_gemm_pA_part<<<dim3(Dm / NB, NT / MB, 8), 256, 0, stream>>>(
                ffhh, ffhl, sw2 + (size_t)std_i * Dm * Hm, part, NT, Dm, Hm, 8);
            reduce_ln<<<NT, 256, 0, stream>>>(
                part, sb2 + (size_t)std_i * Dm, h, ng, nb, xn, xnh, xnl, 8);
            std_i++;
        }
    }

    if (emb_bf && !arena_in_out) {
        int nblk = (NT / MB) * ((Vm + NB - 1) / NB);
        mfma_gemm_bf<<<dim3(nblk), 256, 0, stream>>>(
            xnh, emb_bf, (float*)d_out, NT, Vm, Dm);
    } else {
        mfma_gemm<<<dim3((Vm + NB - 1) / NB, NT / MB), 256, 0, stream>>>(
            xn, emb, (float*)d_out, NT, Vm, Dm);
    }
}

// Round 18
// 1048.360 us; speedup vs baseline: 1.3623x; 1.3623x over previous
//
#include <hip/hip_runtime.h>
#include <hip/hip_bf16.h>
#include <cstdint>
#include <cstddef>

// ---- Model constants ----
#define Dm   768
#define NHm  12
#define Lm   4
#define Em   8
#define Vm   50257
#define Hm   3072
#define Tm   512
#define Bm   2
#define NT   (Bm*Tm)      // 1024 tokens
#define NAS  (NT*2)       // 2048 expert assignments

typedef float f32x4 __attribute__((ext_vector_type(4)));
typedef short bf16x8 __attribute__((ext_vector_type(8)));

__device__ __forceinline__ float gelu_exact(float x) {
    return 0.5f * x * (1.0f + erff(x * 0.70710678118654752440f));
}

__device__ __forceinline__ unsigned short f2bf(float f) {
    __hip_bfloat16 h = __float2bfloat16(f);
    union { __hip_bfloat16 h; unsigned short s; } c; c.h = h; return c.s;
}
__device__ __forceinline__ float bf2f_bits(unsigned short b) {
    union { unsigned u; float f; } c; c.u = ((unsigned)b) << 16; return c.f;
}

// ---------------- fp32 -> bf16 bulk convert (emb only) ----------------
__global__ __launch_bounds__(256) void cvt_bf16_kernel(const float* __restrict__ in,
                                                       unsigned short* __restrict__ out,
                                                       long n) {
    long i = ((long)blockIdx.x * 256 + threadIdx.x) * 8;
    if (i + 8 <= n) {
        const float4* s4 = reinterpret_cast<const float4*>(in + i);
        float4 f0 = s4[0], f1 = s4[1];
        union { unsigned short s[8]; uint4 v; } p;
        p.s[0] = f2bf(f0.x); p.s[1] = f2bf(f0.y); p.s[2] = f2bf(f0.z); p.s[3] = f2bf(f0.w);
        p.s[4] = f2bf(f1.x); p.s[5] = f2bf(f1.y); p.s[6] = f2bf(f1.z); p.s[7] = f2bf(f1.w);
        *reinterpret_cast<uint4*>(out + i) = p.v;
    } else {
        for (long j = i; j < n; ++j) out[j] = f2bf(in[j]);
    }
}

// ---------------- Embedding + sinusoidal PE ----------------
__global__ __launch_bounds__(256) void embed_kernel(const int* __restrict__ x,
                                                    const float* __restrict__ emb,
                                                    float* __restrict__ h) {
    int g = blockIdx.x;
    int tid = threadIdx.x;
    int tok = x[g];
    int pos = g % Tm;
    const float* erow = emb + (size_t)tok * Dm;
    for (int d = tid; d < Dm; d += 256) {
        int i2 = (d >> 1) * 2;
        float div = expf(-logf(10000.0f) * (float)i2 / (float)Dm);
        float a = (float)pos * div;
        float pe = (d & 1) ? cosf(a) : sinf(a);
        h[(size_t)g * Dm + d] = erow[d] + pe;
    }
}

// ---------------- LayerNorm: fp32 xn + hi/lo bf16 split ----------------
__global__ __launch_bounds__(256) void ln_kernel(const float* __restrict__ in,
                                                 const float* __restrict__ g,
                                                 const float* __restrict__ b,
                                                 float* __restrict__ xn,
                                                 unsigned short* __restrict__ xnh,
                                                 unsigned short* __restrict__ xnl) {
    int t = blockIdx.x, tid = threadIdx.x;
    const float* x = in + (size_t)t * Dm;
    float v0 = x[tid], v1 = x[tid + 256], v2 = x[tid + 512];
    __shared__ float red[256];
    red[tid] = v0 + v1 + v2;
    __syncthreads();
    for (int off = 128; off > 0; off >>= 1) {
        if (tid < off) red[tid] += red[tid + off];
        __syncthreads();
    }
    float mean = red[0] * (1.0f / Dm);
    __syncthreads();
    float d0 = v0 - mean, d1 = v1 - mean, d2 = v2 - mean;
    red[tid] = d0 * d0 + d1 * d1 + d2 * d2;
    __syncthreads();
    for (int off = 128; off > 0; off >>= 1) {
        if (tid < off) red[tid] += red[tid + off];
        __syncthreads();
    }
    float inv = rsqrtf(red[0] * (1.0f / Dm) + 1e-5f);
    float o0 = d0 * inv * g[tid]       + b[tid];
    float o1 = d1 * inv * g[tid + 256] + b[tid + 256];
    float o2 = d2 * inv * g[tid + 512] + b[tid + 512];
    long base = (size_t)t * Dm;
    xn[base + tid] = o0; xn[base + tid + 256] = o1; xn[base + tid + 512] = o2;
    unsigned short h0 = f2bf(o0), h1 = f2bf(o1), h2 = f2bf(o2);
    xnh[base + tid] = h0; xnh[base + tid + 256] = h1; xnh[base + tid + 512] = h2;
    xnl[base + tid]       = f2bf(o0 - bf2f_bits(h0));
    xnl[base + tid + 256] = f2bf(o1 - bf2f_bits(h1));
    xnl[base + tid + 512] = f2bf(o2 - bf2f_bits(h2));
}

// ============ MFMA GEMM machinery ============
#define MB 128
#define NB 128
#define KB 32
#define LDT 40

__device__ __forceinline__ void stage_tile(unsigned short* lds, const float* src,
                                           bool valid, int srow, int shalf) {
    union { unsigned short s[8]; uint4 v; } p0, p1;
    if (valid) {
        const float4* s4 = reinterpret_cast<const float4*>(src);
        #pragma unroll
        for (int q = 0; q < 4; ++q) {
            float4 f = s4[q];
            float vv[4] = {f.x, f.y, f.z, f.w};
            #pragma unroll
            for (int j = 0; j < 4; ++j) {
                int idx = q * 4 + j;
                unsigned short hb = f2bf(vv[j]);
                if (idx < 8) p0.s[idx] = hb; else p1.s[idx - 8] = hb;
            }
        }
    } else {
        p0.v = make_uint4(0, 0, 0, 0);
        p1.v = make_uint4(0, 0, 0, 0);
    }
    uint4* dst = reinterpret_cast<uint4*>(&lds[srow * LDT + shalf * 16]);
    dst[0] = p0.v; dst[1] = p1.v;
}

__device__ __forceinline__ void stage_tile_split(unsigned short* lds_hi,
                                                 unsigned short* lds_lo,
                                                 const float* src,
                                                 bool valid, int srow, int shalf) {
    union { unsigned short s[8]; uint4 v; } h0, h1, l0, l1;
    if (valid) {
        const float4* s4 = reinterpret_cast<const float4*>(src);
        #pragma unroll
        for (int q = 0; q < 4; ++q) {
            float4 f = s4[q];
            float vv[4] = {f.x, f.y, f.z, f.w};
            #pragma unroll
            for (int j = 0; j < 4; ++j) {
                int idx = q * 4 + j;
                unsigned short hb = f2bf(vv[j]);
                unsigned short lb = f2bf(vv[j] - bf2f_bits(hb));
                if (idx < 8) { h0.s[idx] = hb; l0.s[idx] = lb; }
                else         { h1.s[idx - 8] = hb; l1.s[idx - 8] = lb; }
            }
        }
    } else {
        h0.v = make_uint4(0,0,0,0); h1.v = make_uint4(0,0,0,0);
        l0.v = make_uint4(0,0,0,0); l1.v = make_uint4(0,0,0,0);
    }
    uint4* dh = reinterpret_cast<uint4*>(&lds_hi[srow * LDT + shalf * 16]);
    dh[0] = h0.v; dh[1] = h1.v;
    uint4* dl = reinterpret_cast<uint4*>(&lds_lo[srow * LDT + shalf * 16]);
    dl[0] = l0.v; dl[1] = l1.v;
}

// Split 16 fp32 held in registers -> hi/lo bf16 LDS.
__device__ __forceinline__ void stage_split_regs(unsigned short* lds_hi,
                                                 unsigned short* lds_lo,
                                                 const float4* rv,
                                                 int srow, int shalf) {
    union { unsigned short s[8]; uint4 v; } h0, h1, l0, l1;
    #pragma unroll
    for (int q = 0; q < 4; ++q) {
        float vv[4] = {rv[q].x, rv[q].y, rv[q].z, rv[q].w};
        #pragma unroll
        for (int j = 0; j < 4; ++j) {
            int idx = q * 4 + j;
            unsigned short hb = f2bf(vv[j]);
            unsigned short lb = f2bf(vv[j] - bf2f_bits(hb));
            if (idx < 8) { h0.s[idx] = hb; l0.s[idx] = lb; }
            else         { h1.s[idx - 8] = hb; l1.s[idx - 8] = lb; }
        }
    }
    uint4* dh = reinterpret_cast<uint4*>(&lds_hi[srow * LDT + shalf * 16]);
    dh[0] = h0.v; dh[1] = h1.v;
    uint4* dl = reinterpret_cast<uint4*>(&lds_lo[srow * LDT + shalf * 16]);
    dl[0] = l0.v; dl[1] = l1.v;
}

// Copy 16 pre-split bf16 into LDS (pure uint4 copies).
__device__ __forceinline__ void stage_tile_copy(unsigned short* lds,
                                                const unsigned short* src,
                                                bool valid, int srow, int shalf) {
    uint4 a0 = make_uint4(0,0,0,0), a1 = make_uint4(0,0,0,0);
    if (valid) {
        a0 = reinterpret_cast<const uint4*>(src)[0];
        a1 = reinterpret_cast<const uint4*>(src)[1];
    }
    uint4* d = reinterpret_cast<uint4*>(&lds[srow * LDT + shalf * 16]);
    d[0] = a0; d[1] = a1;
}

// ---- Lean all-bf16 MFMA GEMM (logits): XCD swizzle + STATIC depth-2
// register prefetch (named sets, rule-#20-safe) + coalesced epilogue ----
__global__ __launch_bounds__(256) void mfma_gemm_bf(const unsigned short* __restrict__ A,
                                                    const unsigned short* __restrict__ B,
                                                    float* __restrict__ C,
                                                    int M, int N, int K) {
    __shared__ __align__(16) unsigned short SMEM[2 * MB * LDT];
    unsigned short* As = SMEM;
    unsigned short* Bs = SMEM + MB * LDT;
    int tid = threadIdx.x;
    int nt_m = M / MB;
    int total = gridDim.x;
    int bid = blockIdx.x;
    int swz = bid;
    if ((total & 7) == 0) {
        int chunk = total >> 3;
        swz = (bid & 7) * chunk + (bid >> 3);
    }
    int bm = (swz % nt_m) * MB;
    int bn = (swz / nt_m) * NB;
    int srow = tid >> 1, shalf = tid & 1;
    int lane = tid & 63, w = tid >> 6;
    int wr = w >> 1, wc = w & 1;
    int r0 = (lane >> 4) * 4, c0 = lane & 15;
    int kb = (lane >> 4) * 8;

    bool bval = (bn + srow) < N;
    const unsigned short* Ap = A + (size_t)(bm + srow) * K + shalf * 16;
    const unsigned short* Bp = B + (size_t)(bn + srow) * K + shalf * 16;

    int nk = K / KB;          // 24 for K=768 (even)
    // Named register sets: A-set for even steps, B-set for odd steps.
    uint4 raA0, raA1, rbA0, rbA1;
    uint4 raB0, raB1, rbB0, rbB1;
    {
        const uint4* p0 = reinterpret_cast<const uint4*>(Ap);
        raA0 = p0[0]; raA1 = p0[1];
        const uint4* p1 = reinterpret_cast<const uint4*>(Ap + KB);
        raB0 = p1[0]; raB1 = p1[1];
        rbA0 = make_uint4(0,0,0,0); rbA1 = make_uint4(0,0,0,0);
        rbB0 = make_uint4(0,0,0,0); rbB1 = make_uint4(0,0,0,0);
        if (bval) {
            const uint4* q0 = reinterpret_cast<const uint4*>(Bp);
            rbA0 = q0[0]; rbA1 = q0[1];
            const uint4* q1 = reinterpret_cast<const uint4*>(Bp + KB);
            rbB0 = q1[0]; rbB1 = q1[1];
        }
    }

    f32x4 acc[4][4] = {};
    uint4* da = reinterpret_cast<uint4*>(&As[srow * LDT + shalf * 16]);
    uint4* db = reinterpret_cast<uint4*>(&Bs[srow * LDT + shalf * 16]);

    for (int i = 0; i < nk; i += 2) {
        // ---- even step: consume set A, prefetch step i+2 into set A ----
        da[0] = raA0; da[1] = raA1;
        db[0] = rbA0; db[1] = rbA1;
        __syncthreads();
        if (i + 2 < nk) {
            const uint4* pa = reinterpret_cast<const uint4*>(Ap + (i + 2) * KB);
            raA0 = pa[0]; raA1 = pa[1];
            if (bval) {
                const uint4* pb = reinterpret_cast<const uint4*>(Bp + (i + 2) * KB);
                rbA0 = pb[0]; rbA1 = pb[1];
            }
        }
        {
            bf16x8 af[4], bf[4];
            #pragma unroll
            for (int m = 0; m < 4; ++m)
                af[m] = *reinterpret_cast<const bf16x8*>(&As[(wr * 64 + m * 16 + c0) * LDT + kb]);
            #pragma unroll
            for (int n = 0; n < 4; ++n)
                bf[n] = *reinterpret_cast<const bf16x8*>(&Bs[(wc * 64 + n * 16 + c0) * LDT + kb]);
            #pragma unroll
            for (int m = 0; m < 4; ++m)
                #pragma unroll
                for (int n = 0; n < 4; ++n)
                    acc[m][n] = __builtin_amdgcn_mfma_f32_16x16x32_bf16(af[m], bf[n], acc[m][n], 0, 0, 0);
        }
        __syncthreads();

        // ---- odd step: consume set B, prefetch step i+3 into set B ----
        da[0] = raB0; da[1] = raB1;
        db[0] = rbB0; db[1] = rbB1;
        __syncthreads();
        if (i + 3 < nk) {
            const uint4* pa = reinterpret_cast<const uint4*>(Ap + (i + 3) * KB);
            raB0 = pa[0]; raB1 = pa[1];
            if (bval) {
                const uint4* pb = reinterpret_cast<const uint4*>(Bp + (i + 3) * KB);
                rbB0 = pb[0]; rbB1 = pb[1];
            }
        }
        {
            bf16x8 af[4], bf[4];
            #pragma unroll
            for (int m = 0; m < 4; ++m)
                af[m] = *reinterpret_cast<const bf16x8*>(&As[(wr * 64 + m * 16 + c0) * LDT + kb]);
            #pragma unroll
            for (int n = 0; n < 4; ++n)
                bf[n] = *reinterpret_cast<const bf16x8*>(&Bs[(wc * 64 + n * 16 + c0) * LDT + kb]);
            #pragma unroll
            for (int m = 0; m < 4; ++m)
                #pragma unroll
                for (int n = 0; n < 4; ++n)
                    acc[m][n] = __builtin_amdgcn_mfma_f32_16x16x32_bf16(af[m], bf[n], acc[m][n], 0, 0, 0);
        }
        __syncthreads();
    }

    float* Ct = reinterpret_cast<float*>(SMEM);
    float* cw = Ct + w * 1024;
    #pragma unroll
    for (int m = 0; m < 4; ++m) {
        #pragma unroll
        for (int n = 0; n < 4; ++n)
            #pragma unroll
            for (int r = 0; r < 4; ++r)
                cw[(r0 + r) * 64 + n * 16 + c0] = acc[m][n][r];
        #pragma unroll
        for (int ch = 0; ch < 4; ++ch) {
            f32x4 vv = *reinterpret_cast<const f32x4*>(&cw[ch * 256 + lane * 4]);
            int rg = bm + wr * 64 + m * 16 + ch * 4 + (lane >> 4);
            int cg = bn + wc * 64 + (lane & 15) * 4;
            if (cg + 3 < N) {
                *reinterpret_cast<f32x4*>(&C[(size_t)rg * N + cg]) = vv;
            } else {
                #pragma unroll
                for (int e = 0; e < 4; ++e)
                    if (cg + e < N) C[(size_t)rg * N + cg + e] = vv[e];
            }
        }
    }
}

// ---- Plain bf16 MFMA GEMM from fp32 (fallback logits path) ----
__global__ __launch_bounds__(256) void mfma_gemm(const float* __restrict__ A,
                                                 const float* __restrict__ B,
                                                 float* __restrict__ C,
                                                 int M, int N, int K) {
    __shared__ __align__(16) unsigned short As[MB * LDT];
    __shared__ __align__(16) unsigned short Bs[NB * LDT];
    int tid = threadIdx.x;
    int bm = blockIdx.y * MB, bn = blockIdx.x * NB;
    int srow = tid >> 1, shalf = tid & 1;
    int lane = tid & 63, w = tid >> 6;
    int wr = w >> 1, wc = w & 1;
    int r0 = (lane >> 4) * 4, c0 = lane & 15;
    int kb = (lane >> 4) * 8;

    f32x4 acc[4][4] = {};

    for (int kk = 0; kk < K; kk += KB) {
        stage_tile(As, A + (size_t)(bm + srow) * K + kk + shalf * 16, true, srow, shalf);
        bool bval = (bn + srow) < N;
        stage_tile(Bs, B + (size_t)(bn + srow) * K + kk + shalf * 16, bval, srow, shalf);
        __syncthreads();
        bf16x8 af[4], bf[4];
        #pragma unroll
        for (int m = 0; m < 4; ++m)
            af[m] = *reinterpret_cast<const bf16x8*>(&As[(wr * 64 + m * 16 + c0) * LDT + kb]);
        #pragma unroll
        for (int n = 0; n < 4; ++n)
            bf[n] = *reinterpret_cast<const bf16x8*>(&Bs[(wc * 64 + n * 16 + c0) * LDT + kb]);
        #pragma unroll
        for (int m = 0; m < 4; ++m)
            #pragma unroll
            for (int n = 0; n < 4; ++n)
                acc[m][n] = __builtin_amdgcn_mfma_f32_16x16x32_bf16(af[m], bf[n], acc[m][n], 0, 0, 0);
        __syncthreads();
    }

    #pragma unroll
    for (int n = 0; n < 4; ++n) {
        int col = bn + wc * 64 + n * 16 + c0;
        if (col < N) {
            #pragma unroll
            for (int m = 0; m < 4; ++m)
                #pragma unroll
                for (int r = 0; r < 4; ++r) {
                    int row = bm + wr * 64 + m * 16 + r0 + r;
                    C[(size_t)row * N + col] = acc[m][n][r];
                }
        }
    }
}

// ---- Split GEMM, pre-split A + fp32 B, K-SPLIT PARTIAL, register prefetch ----
__global__ __launch_bounds__(256) void mfma_gemm_pA_part(const unsigned short* __restrict__ Ahp,
                                                         const unsigned short* __restrict__ Alp,
                                                         const float* __restrict__ B,
                                                         float* __restrict__ part,
                                                         int M, int N, int K, int KSPLIT) {
    __shared__ __align__(16) unsigned short SMEM[4 * MB * LDT];
    unsigned short* Ah = SMEM;
    unsigned short* Al = SMEM + MB * LDT;
    unsigned short* Bh = SMEM + 2 * MB * LDT;
    unsigned short* Bl = SMEM + 3 * MB * LDT;
    int tid = threadIdx.x;
    int bm = blockIdx.y * MB, bn = blockIdx.x * NB;
    int kc = blockIdx.z;
    int chunk = K / KSPLIT;
    int kbeg = kc * chunk;
    int srow = tid >> 1, shalf = tid & 1;
    int lane = tid & 63, w = tid >> 6;
    int wr = w >> 1, wc = w & 1;
    int r0 = (lane >> 4) * 4, c0 = lane & 15;
    int kb = (lane >> 4) * 8;

    const unsigned short* ApH = Ahp + (size_t)(bm + srow) * K + shalf * 16;
    const unsigned short* ApL = Alp + (size_t)(bm + srow) * K + shalf * 16;
    const float* Bp = B + (size_t)(bn + srow) * K + shalf * 16;

    uint4 rah0 = reinterpret_cast<const uint4*>(ApH + kbeg)[0];
    uint4 rah1 = reinterpret_cast<const uint4*>(ApH + kbeg)[1];
    uint4 ral0 = reinterpret_cast<const uint4*>(ApL + kbeg)[0];
    uint4 ral1 = reinterpret_cast<const uint4*>(ApL + kbeg)[1];
    float4 rbv0 = reinterpret_cast<const float4*>(Bp + kbeg)[0];
    float4 rbv1 = reinterpret_cast<const float4*>(Bp + kbeg)[1];
    float4 rbv2 = reinterpret_cast<const float4*>(Bp + kbeg)[2];
    float4 rbv3 = reinterpret_cast<const float4*>(Bp + kbeg)[3];

    f32x4 acc[4][4] = {};

    for (int kk = kbeg; kk < kbeg + chunk; kk += KB) {
        uint4* dah = reinterpret_cast<uint4*>(&Ah[srow * LDT + shalf * 16]);
        dah[0] = rah0; dah[1] = rah1;
        uint4* dal = reinterpret_cast<uint4*>(&Al[srow * LDT + shalf * 16]);
        dal[0] = ral0; dal[1] = ral1;
        float4 rbv[4] = {rbv0, rbv1, rbv2, rbv3};
        stage_split_regs(Bh, Bl, rbv, srow, shalf);
        __syncthreads();
        if (kk + KB < kbeg + chunk) {
            int kn = kk + KB;
            rah0 = reinterpret_cast<const uint4*>(ApH + kn)[0];
            rah1 = reinterpret_cast<const uint4*>(ApH + kn)[1];
            ral0 = reinterpret_cast<const uint4*>(ApL + kn)[0];
            ral1 = reinterpret_cast<const uint4*>(ApL + kn)[1];
            rbv0 = reinterpret_cast<const float4*>(Bp + kn)[0];
            rbv1 = reinterpret_cast<const float4*>(Bp + kn)[1];
            rbv2 = reinterpret_cast<const float4*>(Bp + kn)[2];
            rbv3 = reinterpret_cast<const float4*>(Bp + kn)[3];
        }
        bf16x8 ah[4], al[4], bh[4], bl[4];
        #pragma unroll
        for (int m = 0; m < 4; ++m) {
            int o = (wr * 64 + m * 16 + c0) * LDT + kb;
            ah[m] = *reinterpret_cast<const bf16x8*>(&Ah[o]);
            al[m] = *reinterpret_cast<const bf16x8*>(&Al[o]);
        }
        #pragma unroll
        for (int n = 0; n < 4; ++n) {
            int o = (wc * 64 + n * 16 + c0) * LDT + kb;
            bh[n] = *reinterpret_cast<const bf16x8*>(&Bh[o]);
            bl[n] = *reinterpret_cast<const bf16x8*>(&Bl[o]);
        }
        #pragma unroll
        for (int m = 0; m < 4; ++m)
            #pragma unroll
            for (int n = 0; n < 4; ++n) {
                acc[m][n] = __builtin_amdgcn_mfma_f32_16x16x32_bf16(al[m], bh[n], acc[m][n], 0, 0, 0);
                acc[m][n] = __builtin_amdgcn_mfma_f32_16x16x32_bf16(ah[m], bl[n], acc[m][n], 0, 0, 0);
                acc[m][n] = __builtin_amdgcn_mfma_f32_16x16x32_bf16(ah[m], bh[n], acc[m][n], 0, 0, 0);
            }
        __syncthreads();
    }

    float* Ct = reinterpret_cast<float*>(SMEM);
    float* cw = Ct + w * 1024;
    float* P = part + (size_t)kc * M * N;
    #pragma unroll
    for (int m = 0; m < 4; ++m) {
        #pragma unroll
        for (int n = 0; n < 4; ++n)
            #pragma unroll
            for (int r = 0; r < 4; ++r)
                cw[(r0 + r) * 64 + n * 16 + c0] = acc[m][n][r];
        #pragma unroll
        for (int ch = 0; ch < 4; ++ch) {
            f32x4 vv = *reinterpret_cast<const f32x4*>(&cw[ch * 256 + lane * 4]);
            int rg = bm + wr * 64 + m * 16 + ch * 4 + (lane >> 4);
            int cg = bn + wc * 64 + (lane & 15) * 4;
            *reinterpret_cast<f32x4*>(&P[(size_t)rg * N + cg]) = vv;
        }
    }
}

// ---- Dense reduce (fp32 out, no act): qkv ----
__global__ __launch_bounds__(256) void reduce_dense(const float* __restrict__ part,
                                                    const float* __restrict__ bias,
                                                    float* __restrict__ C,
                                                    long MN, int N, int KSPLIT) {
    long stride = (long)gridDim.x * 256 * 4;
    for (long i = ((long)blockIdx.x * 256 + threadIdx.x) * 4; i < MN; i += stride) {
        float4 v = *reinterpret_cast<const float4*>(part + i);
        for (int kc = 1; kc < KSPLIT; ++kc) {
            float4 p = *reinterpret_cast<const float4*>(part + (size_t)kc * MN + i);
            v.x += p.x; v.y += p.y; v.z += p.z; v.w += p.w;
        }
        int col = (int)(i % N);
        float4 b = *reinterpret_cast<const float4*>(bias + col);
        v.x += b.x; v.y += b.y; v.z += b.z; v.w += b.w;
        *reinterpret_cast<float4*>(C + i) = v;
    }
}

// ---- FFN1 reduce: gelu(Σ parts + bias) -> hi/lo bf16 ----
__global__ __launch_bounds__(256) void reduce_gelu_bf(const float* __restrict__ part,
                                                      const float* __restrict__ bias,
                                                      unsigned short* __restrict__ outh,
                                                      unsigned short* __restrict__ outl,
                                                      long MN, int N, int KSPLIT) {
    long stride = (long)gridDim.x * 256 * 4;
    for (long i = ((long)blockIdx.x * 256 + threadIdx.x) * 4; i < MN; i += stride) {
        float4 v = *reinterpret_cast<const float4*>(part + i);
        for (int kc = 1; kc < KSPLIT; ++kc) {
            float4 p = *reinterpret_cast<const float4*>(part + (size_t)kc * MN + i);
            v.x += p.x; v.y += p.y; v.z += p.z; v.w += p.w;
        }
        int col = (int)(i % N);
        float4 b = *reinterpret_cast<const float4*>(bias + col);
        float f[4];
        f[0] = gelu_exact(v.x + b.x); f[1] = gelu_exact(v.y + b.y);
        f[2] = gelu_exact(v.z + b.z); f[3] = gelu_exact(v.w + b.w);
        union { unsigned short s[4]; uint2 u; } ph, pl;
        #pragma unroll
        for (int e = 0; e < 4; ++e) {
            unsigned short hb = f2bf(f[e]);
            ph.s[e] = hb;
            pl.s[e] = f2bf(f[e] - bf2f_bits(hb));
        }
        *reinterpret_cast<uint2*>(outh + i) = ph.u;
        *reinterpret_cast<uint2*>(outl + i) = pl.u;
    }
}

// ---- Fused reduce(+bias+res into h) + LN -> xn (fp32) + xn hi/lo ----
__global__ __launch_bounds__(256) void reduce_ln(const float* __restrict__ part,
                                                 const float* __restrict__ bias,
                                                 float* __restrict__ h,
                                                 const float* __restrict__ g,
                                                 const float* __restrict__ b,
                                                 float* __restrict__ xn,
                                                 unsigned short* __restrict__ xnh,
                                                 unsigned short* __restrict__ xnl,
                                                 int KSPLIT) {
    const long MN = (long)NT * Dm;
    int t = blockIdx.x, tid = threadIdx.x;
    float v[3];
    #pragma unroll
    for (int j = 0; j < 3; ++j) {
        int col = tid + j * 256;
        long idx = (long)t * Dm + col;
        float s = part[idx];
        for (int kc = 1; kc < KSPLIT; ++kc) s += part[(size_t)kc * MN + idx];
        s += bias[col] + h[idx];
        h[idx] = s;
        v[j] = s;
    }
    __shared__ float red[256];
    red[tid] = v[0] + v[1] + v[2];
    __syncthreads();
    for (int off = 128; off > 0; off >>= 1) {
        if (tid < off) red[tid] += red[tid + off];
        __syncthreads();
    }
    float mean = red[0] * (1.0f / Dm);
    __syncthreads();
    float d0 = v[0] - mean, d1 = v[1] - mean, d2 = v[2] - mean;
    red[tid] = d0 * d0 + d1 * d1 + d2 * d2;
    __syncthreads();
    for (int off = 128; off > 0; off >>= 1) {
        if (tid < off) red[tid] += red[tid + off];
        __syncthreads();
    }
    float inv = rsqrtf(red[0] * (1.0f / Dm) + 1e-5f);
    float o0 = d0 * inv * g[tid]       + b[tid];
    float o1 = d1 * inv * g[tid + 256] + b[tid + 256];
    float o2 = d2 * inv * g[tid + 512] + b[tid + 512];
    long base = (size_t)t * Dm;
    xn[base + tid] = o0; xn[base + tid + 256] = o1; xn[base + tid + 512] = o2;
    unsigned short h0 = f2bf(o0), h1 = f2bf(o1), h2 = f2bf(o2);
    xnh[base + tid] = h0; xnh[base + tid + 256] = h1; xnh[base + tid + 512] = h2;
    xnl[base + tid]       = f2bf(o0 - bf2f_bits(h0));
    xnl[base + tid + 256] = f2bf(o1 - bf2f_bits(h1));
    xnl[base + tid + 512] = f2bf(o2 - bf2f_bits(h2));
}

// ---- Fused MoE combine + LN -> xn + hi/lo ----
__global__ __launch_bounds__(256) void combine_ln(float* __restrict__ h,
                                                  const float* __restrict__ ye,
                                                  const float* __restrict__ g,
                                                  const float* __restrict__ b,
                                                  float* __restrict__ xn,
                                                  unsigned short* __restrict__ xnh,
                                                  unsigned short* __restrict__ xnl) {
    int t = blockIdx.x, tid = threadIdx.x;
    float v[3];
    #pragma unroll
    for (int j = 0; j < 3; ++j) {
        int col = tid + j * 256;
        long idx = (long)t * Dm + col;
        float s = h[idx] + ye[(size_t)(t * 2) * Dm + col] + ye[(size_t)(t * 2 + 1) * Dm + col];
        h[idx] = s;
        v[j] = s;
    }
    __shared__ float red[256];
    red[tid] = v[0] + v[1] + v[2];
    __syncthreads();
    for (int off = 128; off > 0; off >>= 1) {
        if (tid < off) red[tid] += red[tid + off];
        __syncthreads();
    }
    float mean = red[0] * (1.0f / Dm);
    __syncthreads();
    float d0 = v[0] - mean, d1 = v[1] - mean, d2 = v[2] - mean;
    red[tid] = d0 * d0 + d1 * d1 + d2 * d2;
    __syncthreads();
    for (int off = 128; off > 0; off >>= 1) {
        if (tid < off) red[tid] += red[tid + off];
        __syncthreads();
    }
    float inv = rsqrtf(red[0] * (1.0f / Dm) + 1e-5f);
    float o0 = d0 * inv * g[tid]       + b[tid];
    float o1 = d1 * inv * g[tid + 256] + b[tid + 256];
    float o2 = d2 * inv * g[tid + 512] + b[tid + 512];
    long base = (size_t)t * Dm;
    xn[base + tid] = o0; xn[base + tid + 256] = o1; xn[base + tid + 512] = o2;
    unsigned short h0 = f2bf(o0), h1 = f2bf(o1), h2 = f2bf(o2);
    xnh[base + tid] = h0; xnh[base + tid + 256] = h1; xnh[base + tid + 512] = h2;
    xnl[base + tid]       = f2bf(o0 - bf2f_bits(h0));
    xnl[base + tid + 256] = f2bf(o1 - bf2f_bits(h1));
    xnl[base + tid + 512] = f2bf(o2 - bf2f_bits(h2));
}

// ---------------- Flash attention, split-bf16 MFMA; outputs hi/lo bf16 ----------------
#define LDA 72
__device__ __forceinline__ void stage16a(unsigned short* dh, unsigned short* dl,
                                         const float* src) {
    union { unsigned short s[8]; uint4 v; } h0, h1, l0, l1;
    const float4* s4 = reinterpret_cast<const float4*>(src);
    #pragma unroll
    for (int q = 0; q < 4; ++q) {
        float4 f = s4[q];
        float vv[4] = {f.x, f.y, f.z, f.w};
        #pragma unroll
        for (int j = 0; j < 4; ++j) {
            int idx = q * 4 + j;
            unsigned short hb = f2bf(vv[j]);
            unsigned short lb = f2bf(vv[j] - bf2f_bits(hb));
            if (idx < 8) { h0.s[idx] = hb; l0.s[idx] = lb; }
            else         { h1.s[idx - 8] = hb; l1.s[idx - 8] = lb; }
        }
    }
    reinterpret_cast<uint4*>(dh)[0] = h0.v; reinterpret_cast<uint4*>(dh)[1] = h1.v;
    reinterpret_cast<uint4*>(dl)[0] = l0.v; reinterpret_cast<uint4*>(dl)[1] = l1.v;
}

__global__ __launch_bounds__(256) void attn_flash(const float* __restrict__ qkv,
                                                  unsigned short* __restrict__ aoh,
                                                  unsigned short* __restrict__ aol) {
    int qt = blockIdx.x;
    int bh = blockIdx.y;
    int b = bh / NHm, hh = bh % NHm;
    const int g0 = b * Tm;
    const int hoff = hh * 64;
    int tid = threadIdx.x;
    int lane = tid & 63, w = tid >> 6;
    int c0 = lane & 15, hi4 = lane >> 4;
    int kb = hi4 * 8;

    __shared__ __align__(16) unsigned short Qh[64 * LDA], Ql[64 * LDA];
    __shared__ __align__(16) unsigned short Kh[64 * LDA], Kl[64 * LDA];
    __shared__ __align__(16) unsigned short Vh[64 * LDA], Vl[64 * LDA];
    __shared__ __align__(16) unsigned short Ph[4][16 * LDA], Pl[4][16 * LDA];

    {
        int srow = tid >> 2, q = tid & 3;
        stage16a(&Qh[srow * LDA + q * 16], &Ql[srow * LDA + q * 16],
                 qkv + (size_t)(g0 + qt * 64 + srow) * (3 * Dm) + hoff + q * 16);
    }
    __syncthreads();

    f32x4 acc_o[4] = {};
    float m_r[4] = {-1e30f, -1e30f, -1e30f, -1e30f};
    float l_r[4] = {0.f, 0.f, 0.f, 0.f};

    for (int kt = 0; kt <= qt; ++kt) {
        {
            int srow = tid >> 2, q = tid & 3;
            stage16a(&Kh[srow * LDA + q * 16], &Kl[srow * LDA + q * 16],
                     qkv + (size_t)(g0 + kt * 64 + srow) * (3 * Dm) + Dm + hoff + q * 16);
        }
        {
            int d = lane, kg = w;
            const float* vbase = qkv + (size_t)(g0 + kt * 64 + kg * 16) * (3 * Dm) + 2 * Dm + hoff + d;
            #pragma unroll
            for (int k2 = 0; k2 < 16; ++k2) {
                float v = vbase[(size_t)k2 * (3 * Dm)];
                unsigned short hb = f2bf(v);
                Vh[d * LDA + kg * 16 + k2] = hb;
                Vl[d * LDA + kg * 16 + k2] = f2bf(v - bf2f_bits(hb));
            }
        }
        __syncthreads();

        f32x4 sAcc[4] = {};
        #pragma unroll
        for (int kk2 = 0; kk2 < 64; kk2 += 32) {
            bf16x8 ah = *reinterpret_cast<const bf16x8*>(&Qh[(w * 16 + c0) * LDA + kk2 + kb]);
            bf16x8 al = *reinterpret_cast<const bf16x8*>(&Ql[(w * 16 + c0) * LDA + kk2 + kb]);
            #pragma unroll
            for (int n = 0; n < 4; ++n) {
                bf16x8 bh_ = *reinterpret_cast<const bf16x8*>(&Kh[(n * 16 + c0) * LDA + kk2 + kb]);
                bf16x8 bl_ = *reinterpret_cast<const bf16x8*>(&Kl[(n * 16 + c0) * LDA + kk2 + kb]);
                sAcc[n] = __builtin_amdgcn_mfma_f32_16x16x32_bf16(al, bh_, sAcc[n], 0, 0, 0);
                sAcc[n] = __builtin_amdgcn_mfma_f32_16x16x32_bf16(ah, bl_, sAcc[n], 0, 0, 0);
                sAcc[n] = __builtin_amdgcn_mfma_f32_16x16x32_bf16(ah, bh_, sAcc[n], 0, 0, 0);
            }
        }

        float p[4][4];
        float smax[4] = {-3e38f, -3e38f, -3e38f, -3e38f};
        #pragma unroll
        for (int n = 0; n < 4; ++n)
            #pragma unroll
            for (int r = 0; r < 4; ++r) {
                float s = sAcc[n][r] * 0.125f;
                if (kt == qt) {
                    int kg = n * 16 + c0;
                    int qg = w * 16 + hi4 * 4 + r;
                    if (kg > qg) s = -3e38f;
                }
                p[n][r] = s;
                smax[r] = fmaxf(smax[r], s);
            }
        #pragma unroll
        for (int off = 1; off < 16; off <<= 1)
            #pragma unroll
            for (int r = 0; r < 4; ++r)
                smax[r] = fmaxf(smax[r], __shfl_xor(smax[r], off));
        float f_r[4], lsum[4];
        #pragma unroll
        for (int r = 0; r < 4; ++r) {
            float mn = fmaxf(m_r[r], smax[r]);
            f_r[r] = expf(m_r[r] - mn);
            m_r[r] = mn;
        }
        #pragma unroll
        for (int n = 0; n < 4; ++n)
            #pragma unroll
            for (int r = 0; r < 4; ++r)
                p[n][r] = expf(p[n][r] - m_r[r]);
        #pragma unroll
        for (int r = 0; r < 4; ++r)
            lsum[r] = p[0][r] + p[1][r] + p[2][r] + p[3][r];
        #pragma unroll
        for (int off = 1; off < 16; off <<= 1)
            #pragma unroll
            for (int r = 0; r < 4; ++r)
                lsum[r] += __shfl_xor(lsum[r], off);
        #pragma unroll
        for (int r = 0; r < 4; ++r)
            l_r[r] = l_r[r] * f_r[r] + lsum[r];
        #pragma unroll
        for (int n = 0; n < 4; ++n)
            #pragma unroll
            for (int r = 0; r < 4; ++r)
                acc_o[n][r] *= f_r[r];

        #pragma unroll
        for (int n = 0; n < 4; ++n)
            #pragma unroll
            for (int r = 0; r < 4; ++r) {
                unsigned short hb = f2bf(p[n][r]);
                int o = (hi4 * 4 + r) * LDA + n * 16 + c0;
                Ph[w][o] = hb;
                Pl[w][o] = f2bf(p[n][r] - bf2f_bits(hb));
            }

        #pragma unroll
        for (int kk2 = 0; kk2 < 64; kk2 += 32) {
            bf16x8 pah = *reinterpret_cast<const bf16x8*>(&Ph[w][c0 * LDA + kk2 + kb]);
            bf16x8 pal = *reinterpret_cast<const bf16x8*>(&Pl[w][c0 * LDA + kk2 + kb]);
            #pragma unroll
            for (int n = 0; n < 4; ++n) {
                bf16x8 vbh = *reinterpret_cast<const bf16x8*>(&Vh[(n * 16 + c0) * LDA + kk2 + kb]);
                bf16x8 vbl = *reinterpret_cast<const bf16x8*>(&Vl[(n * 16 + c0) * LDA + kk2 + kb]);
                acc_o[n] = __builtin_amdgcn_mfma_f32_16x16x32_bf16(pal, vbh, acc_o[n], 0, 0, 0);
                acc_o[n] = __builtin_amdgcn_mfma_f32_16x16x32_bf16(pah, vbl, acc_o[n], 0, 0, 0);
                acc_o[n] = __builtin_amdgcn_mfma_f32_16x16x32_bf16(pah, vbh, acc_o[n], 0, 0, 0);
            }
        }
        __syncthreads();
    }

    float inv[4];
    #pragma unroll
    for (int r = 0; r < 4; ++r) inv[r] = 1.0f / l_r[r];
    #pragma unroll
    for (int n = 0; n < 4; ++n)
        #pragma unroll
        for (int r = 0; r < 4; ++r) {
            int row = g0 + qt * 64 + w * 16 + hi4 * 4 + r;
            float v = acc_o[n][r] * inv[r];
            unsigned short hb = f2bf(v);
            size_t idx = (size_t)row * Dm + hoff + n * 16 + c0;
            aoh[idx] = hb;
            aol[idx] = f2bf(v - bf2f_bits(hb));
        }
}

// ---------------- MoE router: wave-parallel (fp32 xn) ----------------
__global__ __launch_bounds__(256) void router_kernel(const float* __restrict__ xn,
                                                     const float* __restrict__ gw,
                                                     int* __restrict__ topi,
                                                     float* __restrict__ topw) {
    int t = blockIdx.x * 4 + (threadIdx.x >> 6);
    int lane = threadIdx.x & 63;
    const float4* x4 = reinterpret_cast<const float4*>(xn + (size_t)t * Dm);
    float4 xv[3];
    #pragma unroll
    for (int i = 0; i < 3; ++i) xv[i] = x4[lane + i * 64];

    float l[Em];
    #pragma unroll
    for (int e = 0; e < Em; ++e) {
        const float4* w4 = reinterpret_cast<const float4*>(gw + (size_t)e * Dm);
        float dot = 0.f;
        #pragma unroll
        for (int i = 0; i < 3; ++i) {
            float4 wv = w4[lane + i * 64];
            dot += xv[i].x * wv.x + xv[i].y * wv.y + xv[i].z * wv.z + xv[i].w * wv.w;
        }
        #pragma unroll
        for (int off = 32; off > 0; off >>= 1) dot += __shfl_xor(dot, off);
        l[e] = dot;
    }
    if (lane == 0) {
        int i1 = 0;
        #pragma unroll
        for (int e = 1; e < Em; ++e) if (l[e] > l[i1]) i1 = e;
        int i2 = (i1 == 0) ? 1 : 0;
        #pragma unroll
        for (int e = 0; e < Em; ++e) if (e != i1 && l[e] > l[i2]) i2 = e;
        float w1 = 1.0f / (1.0f + expf(l[i2] - l[i1]));
        topi[t * 2] = i1; topi[t * 2 + 1] = i2;
        topw[t * 2] = w1; topw[t * 2 + 1] = 1.0f - w1;
    }
}

// ---------------- Route build ----------------
__global__ __launch_bounds__(256) void route_build_kernel(const int* __restrict__ topi,
                                                          int* __restrict__ g_cnt,
                                                          int* __restrict__ g_off,
                                                          int* __restrict__ bucket) {
    __shared__ int cnt[Em], off[Em], pos[Em];
    int tid = threadIdx.x;
    if (tid < Em) cnt[tid] = 0;
    __syncthreads();
    for (int ts = tid; ts < NAS; ts += 256) atomicAdd(&cnt[topi[ts]], 1);
    __syncthreads();
    if (tid == 0) {
        int acc = 0;
        for (int e = 0; e < Em; ++e) { off[e] = acc; pos[e] = acc; acc += cnt[e]; }
    }
    __syncthreads();
    for (int ts = tid; ts < NAS; ts += 256) {
        int e = topi[ts];
        int p = atomicAdd(&pos[e], 1);
        bucket[p] = ts;
    }
    if (tid < Em) { g_cnt[tid] = cnt[tid]; g_off[tid] = off[tid]; }
}

// ---------------- Grouped MoE GEMM1: A = xn hi/lo, B = fp32 weights; out heg hi/lo ----
template<int SPLIT>
__global__ __launch_bounds__(256) void moe_mfma_gemm1(const unsigned short* __restrict__ xnh,
                                                      const unsigned short* __restrict__ xnl,
                                                      const float* __restrict__ W1all,
                                                      const float* __restrict__ B1all,
                                                      const int* __restrict__ bucket,
                                                      const int* __restrict__ cnt,
                                                      const int* __restrict__ off,
                                                      unsigned short* __restrict__ hegh,
                                                      unsigned short* __restrict__ hegl) {
    int e = blockIdx.z;
    int count = cnt[e];
    int mbase = blockIdx.y * MB;
    if (mbase >= count) return;
    int base = off[e];

    __shared__ __align__(16) unsigned short Ah[MB * LDT];
    __shared__ __align__(16) unsigned short Bh[NB * LDT];
    __shared__ __align__(16) unsigned short Al[SPLIT ? MB * LDT : 8];
    __shared__ __align__(16) unsigned short Bl[SPLIT ? NB * LDT : 8];
    __shared__ int toks[MB];
    int tid = threadIdx.x;
    int bn = blockIdx.x * NB;
    int srow = tid >> 1, shalf = tid & 1;
    int lane = tid & 63, w = tid >> 6;
    int wr = w >> 1, wc = w & 1;
    int r0 = (lane >> 4) * 4, c0 = lane & 15;
    int kb = (lane >> 4) * 8;
    if (tid < MB) {
        int p = mbase + tid;
        toks[tid] = (p < count) ? (bucket[base + p] >> 1) : -1;
    }
    __syncthreads();

    f32x4 acc[4][4] = {};
    const float* W = W1all + (size_t)e * Hm * Dm;
    int t = toks[srow];
    for (int kk = 0; kk < Dm; kk += KB) {
        size_t aoff = (size_t)t * Dm + kk + shalf * 16;
        stage_tile_copy(Ah, xnh + aoff, t >= 0, srow, shalf);
        if (SPLIT) {
            stage_tile_copy(Al, xnl + aoff, t >= 0, srow, shalf);
            stage_tile_split(Bh, Bl, W + (size_t)(bn + srow) * Dm + kk + shalf * 16, true, srow, shalf);
        } else {
            stage_tile(Bh, W + (size_t)(bn + srow) * Dm + kk + shalf * 16, true, srow, shalf);
        }
        __syncthreads();
        bf16x8 ah[4], bh[4], al[4], bl[4];
        #pragma unroll
        for (int m = 0; m < 4; ++m) {
            int o = (wr * 64 + m * 16 + c0) * LDT + kb;
            ah[m] = *reinterpret_cast<const bf16x8*>(&Ah[o]);
            if (SPLIT) al[m] = *reinterpret_cast<const bf16x8*>(&Al[o]);
        }
        #pragma unroll
        for (int n = 0; n < 4; ++n) {
            int o = (wc * 64 + n * 16 + c0) * LDT + kb;
            bh[n] = *reinterpret_cast<const bf16x8*>(&Bh[o]);
            if (SPLIT) bl[n] = *reinterpret_cast<const bf16x8*>(&Bl[o]);
        }
        #pragma unroll
        for (int m = 0; m < 4; ++m)
            #pragma unroll
            for (int n = 0; n < 4; ++n) {
                if (SPLIT) {
                    acc[m][n] = __builtin_amdgcn_mfma_f32_16x16x32_bf16(al[m], bh[n], acc[m][n], 0, 0, 0);
                    acc[m][n] = __builtin_amdgcn_mfma_f32_16x16x32_bf16(ah[m], bl[n], acc[m][n], 0, 0, 0);
                }
                acc[m][n] = __builtin_amdgcn_mfma_f32_16x16x32_bf16(ah[m], bh[n], acc[m][n], 0, 0, 0);
            }
        __syncthreads();
    }

    const float* b1 = B1all + (size_t)e * Hm;
    #pragma unroll
    for (int n = 0; n < 4; ++n) {
        int col = bn + wc * 64 + n * 16 + c0;
        float bv = b1[col];
        #pragma unroll
        for (int m = 0; m < 4; ++m) {
            #pragma unroll
            for (int r = 0; r < 4; ++r) {
                int p = mbase + wr * 64 + m * 16 + r0 + r;
                if (p < count) {
                    float v = gelu_exact(acc[m][n][r] + bv);
                    unsigned short hb = f2bf(v);
                    size_t idx = (size_t)(base + p) * Hm + col;
                    hegh[idx] = hb;
                    hegl[idx] = f2bf(v - bf2f_bits(hb));
                }
            }
        }
    }
}

// ---------------- Grouped MoE GEMM2: A = heg hi/lo, B = fp32; K-SPLIT partial ----
template<int SPLIT>
__global__ __launch_bounds__(256) void moe_gemm2_part(const unsigned short* __restrict__ hegh,
                                                      const unsigned short* __restrict__ hegl,
                                                      const float* __restrict__ W2all,
                                                      const int* __restrict__ cnt,
                                                      const int* __restrict__ off,
                                                      float* __restrict__ part,
                                                      int KSPLIT) {
    int e = blockIdx.z;
    int count = cnt[e];
    int my = blockIdx.y;
    int kc = my % KSPLIT, mb = my / KSPLIT;
    int mbase = mb * MB;
    if (mbase >= count) return;
    int base = off[e];
    int chunk = Hm / KSPLIT;
    int kbeg = kc * chunk;

    __shared__ __align__(16) unsigned short Ah[MB * LDT];
    __shared__ __align__(16) unsigned short Bh[NB * LDT];
    __shared__ __align__(16) unsigned short Al[SPLIT ? MB * LDT : 8];
    __shared__ __align__(16) unsigned short Bl[SPLIT ? NB * LDT : 8];
    int tid = threadIdx.x;
    int bn = blockIdx.x * NB;
    int srow = tid >> 1, shalf = tid & 1;
    int lane = tid & 63, w = tid >> 6;
    int wr = w >> 1, wc = w & 1;
    int r0 = (lane >> 4) * 4, c0 = lane & 15;
    int kb = (lane >> 4) * 8;

    f32x4 acc[4][4] = {};
    const float* W = W2all + (size_t)e * Dm * Hm;
    bool aval = (mbase + srow) < count;
    for (int kk = kbeg; kk < kbeg + chunk; kk += KB) {
        size_t aoff = (size_t)(base + mbase + srow) * Hm + kk + shalf * 16;
        stage_tile_copy(Ah, hegh + aoff, aval, srow, shalf);
        if (SPLIT) {
            stage_tile_copy(Al, hegl + aoff, aval, srow, shalf);
            stage_tile_split(Bh, Bl, W + (size_t)(bn + srow) * Hm + kk + shalf * 16, true, srow, shalf);
        } else {
            stage_tile(Bh, W + (size_t)(bn + srow) * Hm + kk + shalf * 16, true, srow, shalf);
        }
        __syncthreads();
        bf16x8 ah[4], bh[4], al[4], bl[4];
        #pragma unroll
        for (int m = 0; m < 4; ++m) {
            int o = (wr * 64 + m * 16 + c0) * LDT + kb;
            ah[m] = *reinterpret_cast<const bf16x8*>(&Ah[o]);
            if (SPLIT) al[m] = *reinterpret_cast<const bf16x8*>(&Al[o]);
        }
        #pragma unroll
        for (int n = 0; n < 4; ++n) {
            int o = (wc * 64 + n * 16 + c0) * LDT + kb;
            bh[n] = *reinterpret_cast<const bf16x8*>(&Bh[o]);
            if (SPLIT) bl[n] = *reinterpret_cast<const bf16x8*>(&Bl[o]);
        }
        #pragma unroll
        for (int m = 0; m < 4; ++m)
            #pragma unroll
            for (int n = 0; n < 4; ++n) {
                if (SPLIT) {
                    acc[m][n] = __builtin_amdgcn_mfma_f32_16x16x32_bf16(al[m], bh[n], acc[m][n], 0, 0, 0);
                    acc[m][n] = __builtin_amdgcn_mfma_f32_16x16x32_bf16(ah[m], bl[n], acc[m][n], 0, 0, 0);
                }
                acc[m][n] = __builtin_amdgcn_mfma_f32_16x16x32_bf16(ah[m], bh[n], acc[m][n], 0, 0, 0);
            }
        __syncthreads();
    }

    float* P = part + (size_t)kc * NAS * Dm;
    #pragma unroll
    for (int n = 0; n < 4; ++n) {
        int col = bn + wc * 64 + n * 16 + c0;
        #pragma unroll
        for (int m = 0; m < 4; ++m) {
            #pragma unroll
            for (int r = 0; r < 4; ++r) {
                int p = mbase + wr * 64 + m * 16 + r0 + r;
                if (p < count)
                    P[(size_t)(base + p) * Dm + col] = acc[m][n][r];
            }
        }
    }
}

// ---- MoE reduce: ye[ts] = topw[ts] * (Σ parts + b2[e]) ----
__global__ __launch_bounds__(256) void moe_reduce(const float* __restrict__ part,
                                                  const float* __restrict__ B2all,
                                                  const int* __restrict__ bucket,
                                                  const int* __restrict__ topi,
                                                  const float* __restrict__ topw,
                                                  float* __restrict__ ye, int KSPLIT) {
    const long MN = (long)NAS * Dm;
    long stride = (long)gridDim.x * 256 * 4;
    for (long i = ((long)blockIdx.x * 256 + threadIdx.x) * 4; i < MN; i += stride) {
        int p = (int)(i / Dm), col = (int)(i % Dm);
        int ts = bucket[p];
        int e = topi[ts];
        float wgt = topw[ts];
        float4 v = *reinterpret_cast<const float4*>(part + i);
        for (int kc = 1; kc < KSPLIT; ++kc) {
            float4 q = *reinterpret_cast<const float4*>(part + (size_t)kc * MN + i);
            v.x += q.x; v.y += q.y; v.z += q.z; v.w += q.w;
        }
        float4 b = *reinterpret_cast<const float4*>(B2all + (size_t)e * Dm + col);
        float4 o;
        o.x = wgt * (v.x + b.x); o.y = wgt * (v.y + b.y);
        o.z = wgt * (v.z + b.z); o.w = wgt * (v.w + b.w);
        *reinterpret_cast<float4*>(ye + (size_t)ts * Dm + col) = o;
    }
}

// ---------------- Launch ----------------
extern "C" void kernel_launch(void* const* d_in, const int* in_sizes, int n_in,
                              void* d_out, int out_size, void* d_ws, size_t ws_size,
                              hipStream_t stream) {
    const int*   x    = (const int*)d_in[0];
    const float* emb  = (const float*)d_in[1];
    const float* wqkv = (const float*)d_in[2];
    const float* bqkv = (const float*)d_in[3];
    const float* wo   = (const float*)d_in[4];
    const float* bo   = (const float*)d_in[5];
    const float* ln1g = (const float*)d_in[6];
    const float* ln1b = (const float*)d_in[7];
    const float* ln2g = (const float*)d_in[8];
    const float* ln2b = (const float*)d_in[9];
    const float* sw1  = (const float*)d_in[10];
    const float* sb1  = (const float*)d_in[11];
    const float* sw2  = (const float*)d_in[12];
    const float* sb2  = (const float*)d_in[13];
    const float* gw   = (const float*)d_in[14];
    const float* mw1  = (const float*)d_in[15];
    const float* mb1  = (const float*)d_in[16];
    const float* mw2  = (const float*)d_in[17];
    const float* mb2  = (const float*)d_in[18];
    const float* lnfg = (const float*)d_in[19];
    const float* lnfb = (const float*)d_in[20];

    const size_t n_h    = (size_t)NT * Dm;
    const size_t n_qkv  = (size_t)NT * 3 * Dm;
    const size_t n_ye   = (size_t)NAS * Dm;
    const size_t n_part = (size_t)NT * Hm * 2;
    const size_t n_xnb  = (size_t)NT * Dm / 2;
    const size_t n_ffhb = (size_t)NT * Hm / 2;
    const size_t n_hegb = (size_t)NAS * Hm / 2;
    const size_t n_embbf = (size_t)Vm * Dm / 2;
    const size_t n_big = n_h + n_qkv + n_ye + n_part
                       + 2 * n_xnb + 2 * n_xnb
                       + 2 * n_ffhb + 2 * n_hegb;

    size_t wsf = ws_size / sizeof(float);

    float* w = (float*)d_ws;
    float* xn   = w;            w += (size_t)NT * Dm;
    float* topw = w;            w += NAS;
    int*   topi = (int*)w;      w += NAS;
    int*   bucket = (int*)w;    w += NAS;
    int*   e_cnt = (int*)w;     w += 8;
    int*   e_off = (int*)w;     w += 8;
    size_t used = (size_t)(w - (float*)d_ws);

    unsigned short* emb_bf = nullptr;
    if (wsf >= used + n_embbf + 64) {
        emb_bf = (unsigned short*)w;  w += n_embbf;
        used = (size_t)(w - (float*)d_ws);
    }

    float *h, *qkv, *ye, *part;
    unsigned short *xnh, *xnl, *aoh, *aol, *ffhh, *ffhl, *hegh, *hegl;
    float* a;
    bool arena_in_out;
    if (wsf >= used + n_big + 64) { a = w; arena_in_out = false; }
    else                          { a = (float*)d_out; arena_in_out = true; }
    h = a;      a += n_h;
    qkv = a;    a += n_qkv;
    ye = a;     a += n_ye;
    part = a;   a += n_part;
    xnh = (unsigned short*)a;  a += n_xnb;
    xnl = (unsigned short*)a;  a += n_xnb;
    aoh = (unsigned short*)a;  a += n_xnb;
    aol = (unsigned short*)a;  a += n_xnb;
    ffhh = (unsigned short*)a; a += n_ffhb;
    ffhl = (unsigned short*)a; a += n_ffhb;
    hegh = (unsigned short*)a; a += n_hegb;
    hegl = (unsigned short*)a; a += n_hegb;

    if (emb_bf) {
        long n = (long)Vm * Dm;
        cvt_bf16_kernel<<<(unsigned)((n / 8 + 255) / 256), 256, 0, stream>>>(emb, emb_bf, n);
    }

    embed_kernel<<<NT, 256, 0, stream>>>(x, emb, h);
    ln_kernel<<<NT, 256, 0, stream>>>(h, ln1g, ln1b, xn, xnh, xnl);

    const int RBLK = 2048;
    int std_i = 0, moe_i = 0;
    for (int l = 0; l < Lm; ++l) {
        const float* ng = (l < 3) ? (ln1g + (l + 1) * Dm) : lnfg;
        const float* nb = (l < 3) ? (ln1b + (l + 1) * Dm) : lnfb;

        mfma_gemm_pA_part<<<dim3((3 * Dm) / NB, NT / MB, 2), 256, 0, stream>>>(
            xnh, xnl, wqkv + (size_t)l * 3 * Dm * Dm, part, NT, 3 * Dm, Dm, 2);
        reduce_dense<<<RBLK, 256, 0, stream>>>(
            part, bqkv + (size_t)l * 3 * Dm, qkv, (long)NT * 3 * Dm, 3 * Dm, 2);
        attn_flash<<<dim3(Tm / 64, Bm * NHm), 256, 0, stream>>>(qkv, aoh, aol);
        mfma_gemm_pA_part<<<dim3(Dm / NB, NT / MB, 4), 256, 0, stream>>>(
            aoh, aol, wo + (size_t)l * Dm * Dm, part, NT, Dm, Dm, 4);
        reduce_ln<<<NT, 256, 0, stream>>>(
            part, bo + (size_t)l * Dm, h, ln2g + l * Dm, ln2b + l * Dm, xn, xnh, xnl, 4);

        if (l == 1 || l == 3) {
            router_kernel<<<NT / 4, 256, 0, stream>>>(
                xn, gw + (size_t)moe_i * Em * Dm, topi, topw);
            route_build_kernel<<<1, 256, 0, stream>>>(topi, e_cnt, e_off, bucket);
            if (l == 3) {
                moe_mfma_gemm1<0><<<dim3(Hm / NB, NAS / MB, Em), 256, 0, stream>>>(
                    xnh, xnl, mw1 + (size_t)moe_i * Em * Hm * Dm, mb1 + (size_t)moe_i * Em * Hm,
                    bucket, e_cnt, e_off, hegh, hegl);
                moe_gemm2_part<0><<<dim3(Dm / NB, (NAS / MB) * 4, Em), 256, 0, stream>>>(
                    hegh, hegl, mw2 + (size_t)moe_i * Em * Dm * Hm, e_cnt, e_off, part, 4);
            } else {
                moe_mfma_gemm1<1><<<dim3(Hm / NB, NAS / MB, Em), 256, 0, stream>>>(
                    xnh, xnl, mw1 + (size_t)moe_i * Em * Hm * Dm, mb1 + (size_t)moe_i * Em * Hm,
                    bucket, e_cnt, e_off, hegh, hegl);
                moe_gemm2_part<1><<<dim3(Dm / NB, (NAS / MB) * 4, Em), 256, 0, stream>>>(
                    hegh, hegl, mw2 + (size_t)moe_i * Em * Dm * Hm, e_cnt, e_off, part, 4);
            }
            moe_reduce<<<RBLK, 256, 0, stream>>>(
                part, mb2 + (size_t)moe_i * Em * Dm, bucket, topi, topw, ye, 4);
            combine_ln<<<NT, 256, 0, stream>>>(h, ye, ng, nb, xn, xnh, xnl);
            moe_i++;
        } else {
            mfma_gemm_pA_part<<<dim3(Hm / NB, NT / MB, 2), 256, 0, stream>>>(
                xnh, xnl, sw1 + (size_t)std_i * Hm * Dm, part, NT, Hm, Dm, 2);
            reduce_gelu_bf<<<RBLK, 256, 0, stream>>>(
                part, sb1 + (size_t)std_i * Hm, ffhh, ffhl, (long)NT * Hm, Hm, 2);
            mfma_gemm_pA_part<<<dim3(Dm / NB, NT / MB, 8), 256, 0, stream>>>(
                ffhh, ffhl, sw2 + (size_t)std_i * Dm * Hm, part, NT, Dm, Hm, 8);
            reduce_ln<<<NT, 256, 0, stream>>>(
                part, sb2 + (size_t)std_i * Dm, h, ng, nb, xn, xnh, xnl, 8);
            std_i++;
        }
    }

    if (emb_bf && !arena_in_out) {
        int nblk = (NT / MB) * ((Vm + NB - 1) / NB);
        mfma_gemm_bf<<<dim3(nblk), 256, 0, stream>>>(
            xnh, emb_bf, (float*)d_out, NT, Vm, Dm);
    } else {
        mfma_gemm<<<dim3((Vm + NB - 1) / NB, NT / MB), 256, 0, stream>>>(
            xn, emb, (float*)d_out, NT, Vm, Dm);
    }
}

// Round 19
// 1022.905 us; speedup vs baseline: 1.3962x; 1.0249x over previous
//
#include <hip/hip_runtime.h>
#include <hip/hip_bf16.h>
#include <cstdint>
#include <cstddef>

// ---- Model constants ----
#define Dm   768
#define NHm  12
#define Lm   4
#define Em   8
#define Vm   50257
#define Hm   3072
#define Tm   512
#define Bm   2
#define NT   (Bm*Tm)      // 1024 tokens
#define NAS  (NT*2)       // 2048 expert assignments

typedef float f32x4 __attribute__((ext_vector_type(4)));
typedef short bf16x8 __attribute__((ext_vector_type(8)));

__device__ __forceinline__ float gelu_exact(float x) {
    return 0.5f * x * (1.0f + erff(x * 0.70710678118654752440f));
}

__device__ __forceinline__ unsigned short f2bf(float f) {
    __hip_bfloat16 h = __float2bfloat16(f);
    union { __hip_bfloat16 h; unsigned short s; } c; c.h = h; return c.s;
}
__device__ __forceinline__ float bf2f_bits(unsigned short b) {
    union { unsigned u; float f; } c; c.u = ((unsigned)b) << 16; return c.f;
}

// ---------------- fp32 -> bf16 bulk convert (emb only) ----------------
__global__ __launch_bounds__(256) void cvt_bf16_kernel(const float* __restrict__ in,
                                                       unsigned short* __restrict__ out,
                                                       long n) {
    long i = ((long)blockIdx.x * 256 + threadIdx.x) * 8;
    if (i + 8 <= n) {
        const float4* s4 = reinterpret_cast<const float4*>(in + i);
        float4 f0 = s4[0], f1 = s4[1];
        union { unsigned short s[8]; uint4 v; } p;
        p.s[0] = f2bf(f0.x); p.s[1] = f2bf(f0.y); p.s[2] = f2bf(f0.z); p.s[3] = f2bf(f0.w);
        p.s[4] = f2bf(f1.x); p.s[5] = f2bf(f1.y); p.s[6] = f2bf(f1.z); p.s[7] = f2bf(f1.w);
        *reinterpret_cast<uint4*>(out + i) = p.v;
    } else {
        for (long j = i; j < n; ++j) out[j] = f2bf(in[j]);
    }
}

// ---------------- Embedding + sinusoidal PE ----------------
__global__ __launch_bounds__(256) void embed_kernel(const int* __restrict__ x,
                                                    const float* __restrict__ emb,
                                                    float* __restrict__ h) {
    int g = blockIdx.x;
    int tid = threadIdx.x;
    int tok = x[g];
    int pos = g % Tm;
    const float* erow = emb + (size_t)tok * Dm;
    for (int d = tid; d < Dm; d += 256) {
        int i2 = (d >> 1) * 2;
        float div = expf(-logf(10000.0f) * (float)i2 / (float)Dm);
        float a = (float)pos * div;
        float pe = (d & 1) ? cosf(a) : sinf(a);
        h[(size_t)g * Dm + d] = erow[d] + pe;
    }
}

// ---------------- LayerNorm: fp32 xn + hi/lo bf16 split ----------------
__global__ __launch_bounds__(256) void ln_kernel(const float* __restrict__ in,
                                                 const float* __restrict__ g,
                                                 const float* __restrict__ b,
                                                 float* __restrict__ xn,
                                                 unsigned short* __restrict__ xnh,
                                                 unsigned short* __restrict__ xnl) {
    int t = blockIdx.x, tid = threadIdx.x;
    const float* x = in + (size_t)t * Dm;
    float v0 = x[tid], v1 = x[tid + 256], v2 = x[tid + 512];
    __shared__ float red[256];
    red[tid] = v0 + v1 + v2;
    __syncthreads();
    for (int off = 128; off > 0; off >>= 1) {
        if (tid < off) red[tid] += red[tid + off];
        __syncthreads();
    }
    float mean = red[0] * (1.0f / Dm);
    __syncthreads();
    float d0 = v0 - mean, d1 = v1 - mean, d2 = v2 - mean;
    red[tid] = d0 * d0 + d1 * d1 + d2 * d2;
    __syncthreads();
    for (int off = 128; off > 0; off >>= 1) {
        if (tid < off) red[tid] += red[tid + off];
        __syncthreads();
    }
    float inv = rsqrtf(red[0] * (1.0f / Dm) + 1e-5f);
    float o0 = d0 * inv * g[tid]       + b[tid];
    float o1 = d1 * inv * g[tid + 256] + b[tid + 256];
    float o2 = d2 * inv * g[tid + 512] + b[tid + 512];
    long base = (size_t)t * Dm;
    xn[base + tid] = o0; xn[base + tid + 256] = o1; xn[base + tid + 512] = o2;
    unsigned short h0 = f2bf(o0), h1 = f2bf(o1), h2 = f2bf(o2);
    xnh[base + tid] = h0; xnh[base + tid + 256] = h1; xnh[base + tid + 512] = h2;
    xnl[base + tid]       = f2bf(o0 - bf2f_bits(h0));
    xnl[base + tid + 256] = f2bf(o1 - bf2f_bits(h1));
    xnl[base + tid + 512] = f2bf(o2 - bf2f_bits(h2));
}

// ============ MFMA GEMM machinery ============
#define MB 128
#define NB 128
#define KB 32
#define LDT 40

__device__ __forceinline__ void stage_tile(unsigned short* lds, const float* src,
                                           bool valid, int srow, int shalf) {
    union { unsigned short s[8]; uint4 v; } p0, p1;
    if (valid) {
        const float4* s4 = reinterpret_cast<const float4*>(src);
        #pragma unroll
        for (int q = 0; q < 4; ++q) {
            float4 f = s4[q];
            float vv[4] = {f.x, f.y, f.z, f.w};
            #pragma unroll
            for (int j = 0; j < 4; ++j) {
                int idx = q * 4 + j;
                unsigned short hb = f2bf(vv[j]);
                if (idx < 8) p0.s[idx] = hb; else p1.s[idx - 8] = hb;
            }
        }
    } else {
        p0.v = make_uint4(0, 0, 0, 0);
        p1.v = make_uint4(0, 0, 0, 0);
    }
    uint4* dst = reinterpret_cast<uint4*>(&lds[srow * LDT + shalf * 16]);
    dst[0] = p0.v; dst[1] = p1.v;
}

__device__ __forceinline__ void stage_tile_split(unsigned short* lds_hi,
                                                 unsigned short* lds_lo,
                                                 const float* src,
                                                 bool valid, int srow, int shalf) {
    union { unsigned short s[8]; uint4 v; } h0, h1, l0, l1;
    if (valid) {
        const float4* s4 = reinterpret_cast<const float4*>(src);
        #pragma unroll
        for (int q = 0; q < 4; ++q) {
            float4 f = s4[q];
            float vv[4] = {f.x, f.y, f.z, f.w};
            #pragma unroll
            for (int j = 0; j < 4; ++j) {
                int idx = q * 4 + j;
                unsigned short hb = f2bf(vv[j]);
                unsigned short lb = f2bf(vv[j] - bf2f_bits(hb));
                if (idx < 8) { h0.s[idx] = hb; l0.s[idx] = lb; }
                else         { h1.s[idx - 8] = hb; l1.s[idx - 8] = lb; }
            }
        }
    } else {
        h0.v = make_uint4(0,0,0,0); h1.v = make_uint4(0,0,0,0);
        l0.v = make_uint4(0,0,0,0); l1.v = make_uint4(0,0,0,0);
    }
    uint4* dh = reinterpret_cast<uint4*>(&lds_hi[srow * LDT + shalf * 16]);
    dh[0] = h0.v; dh[1] = h1.v;
    uint4* dl = reinterpret_cast<uint4*>(&lds_lo[srow * LDT + shalf * 16]);
    dl[0] = l0.v; dl[1] = l1.v;
}

// Split 16 fp32 held in registers -> hi/lo bf16 LDS.
__device__ __forceinline__ void stage_split_regs(unsigned short* lds_hi,
                                                 unsigned short* lds_lo,
                                                 const float4* rv,
                                                 int srow, int shalf) {
    union { unsigned short s[8]; uint4 v; } h0, h1, l0, l1;
    #pragma unroll
    for (int q = 0; q < 4; ++q) {
        float vv[4] = {rv[q].x, rv[q].y, rv[q].z, rv[q].w};
        #pragma unroll
        for (int j = 0; j < 4; ++j) {
            int idx = q * 4 + j;
            unsigned short hb = f2bf(vv[j]);
            unsigned short lb = f2bf(vv[j] - bf2f_bits(hb));
            if (idx < 8) { h0.s[idx] = hb; l0.s[idx] = lb; }
            else         { h1.s[idx - 8] = hb; l1.s[idx - 8] = lb; }
        }
    }
    uint4* dh = reinterpret_cast<uint4*>(&lds_hi[srow * LDT + shalf * 16]);
    dh[0] = h0.v; dh[1] = h1.v;
    uint4* dl = reinterpret_cast<uint4*>(&lds_lo[srow * LDT + shalf * 16]);
    dl[0] = l0.v; dl[1] = l1.v;
}

// Copy 16 pre-split bf16 into LDS (pure uint4 copies).
__device__ __forceinline__ void stage_tile_copy(unsigned short* lds,
                                                const unsigned short* src,
                                                bool valid, int srow, int shalf) {
    uint4 a0 = make_uint4(0,0,0,0), a1 = make_uint4(0,0,0,0);
    if (valid) {
        a0 = reinterpret_cast<const uint4*>(src)[0];
        a1 = reinterpret_cast<const uint4*>(src)[1];
    }
    uint4* d = reinterpret_cast<uint4*>(&lds[srow * LDT + shalf * 16]);
    d[0] = a0; d[1] = a1;
}

// ---- Lean all-bf16 MFMA GEMM (logits): XCD swizzle + depth-1 register
// prefetch (low VGPR -> high occupancy; verified best) + coalesced epilogue ----
__global__ __launch_bounds__(256) void mfma_gemm_bf(const unsigned short* __restrict__ A,
                                                    const unsigned short* __restrict__ B,
                                                    float* __restrict__ C,
                                                    int M, int N, int K) {
    __shared__ __align__(16) unsigned short SMEM[2 * MB * LDT];
    unsigned short* As = SMEM;
    unsigned short* Bs = SMEM + MB * LDT;
    int tid = threadIdx.x;
    int nt_m = M / MB;
    int total = gridDim.x;
    int bid = blockIdx.x;
    int swz = bid;
    if ((total & 7) == 0) {
        int chunk = total >> 3;
        swz = (bid & 7) * chunk + (bid >> 3);
    }
    int bm = (swz % nt_m) * MB;
    int bn = (swz / nt_m) * NB;
    int srow = tid >> 1, shalf = tid & 1;
    int lane = tid & 63, w = tid >> 6;
    int wr = w >> 1, wc = w & 1;
    int r0 = (lane >> 4) * 4, c0 = lane & 15;
    int kb = (lane >> 4) * 8;

    bool bval = (bn + srow) < N;
    const unsigned short* Ap = A + (size_t)(bm + srow) * K + shalf * 16;
    const unsigned short* Bp = B + (size_t)(bn + srow) * K + shalf * 16;

    uint4 ra0, ra1, rb0, rb1;
    ra0 = reinterpret_cast<const uint4*>(Ap)[0];
    ra1 = reinterpret_cast<const uint4*>(Ap)[1];
    rb0 = make_uint4(0,0,0,0); rb1 = make_uint4(0,0,0,0);
    if (bval) {
        rb0 = reinterpret_cast<const uint4*>(Bp)[0];
        rb1 = reinterpret_cast<const uint4*>(Bp)[1];
    }

    f32x4 acc[4][4] = {};

    for (int kk = 0; kk < K; kk += KB) {
        uint4* da = reinterpret_cast<uint4*>(&As[srow * LDT + shalf * 16]);
        da[0] = ra0; da[1] = ra1;
        uint4* db = reinterpret_cast<uint4*>(&Bs[srow * LDT + shalf * 16]);
        db[0] = rb0; db[1] = rb1;
        __syncthreads();
        if (kk + KB < K) {
            const uint4* na = reinterpret_cast<const uint4*>(Ap + kk + KB);
            ra0 = na[0]; ra1 = na[1];
            if (bval) {
                const uint4* nb = reinterpret_cast<const uint4*>(Bp + kk + KB);
                rb0 = nb[0]; rb1 = nb[1];
            }
        }
        bf16x8 af[4], bf[4];
        #pragma unroll
        for (int m = 0; m < 4; ++m)
            af[m] = *reinterpret_cast<const bf16x8*>(&As[(wr * 64 + m * 16 + c0) * LDT + kb]);
        #pragma unroll
        for (int n = 0; n < 4; ++n)
            bf[n] = *reinterpret_cast<const bf16x8*>(&Bs[(wc * 64 + n * 16 + c0) * LDT + kb]);
        #pragma unroll
        for (int m = 0; m < 4; ++m)
            #pragma unroll
            for (int n = 0; n < 4; ++n)
                acc[m][n] = __builtin_amdgcn_mfma_f32_16x16x32_bf16(af[m], bf[n], acc[m][n], 0, 0, 0);
        __syncthreads();
    }

    float* Ct = reinterpret_cast<float*>(SMEM);
    float* cw = Ct + w * 1024;
    #pragma unroll
    for (int m = 0; m < 4; ++m) {
        #pragma unroll
        for (int n = 0; n < 4; ++n)
            #pragma unroll
            for (int r = 0; r < 4; ++r)
                cw[(r0 + r) * 64 + n * 16 + c0] = acc[m][n][r];
        #pragma unroll
        for (int ch = 0; ch < 4; ++ch) {
            f32x4 vv = *reinterpret_cast<const f32x4*>(&cw[ch * 256 + lane * 4]);
            int rg = bm + wr * 64 + m * 16 + ch * 4 + (lane >> 4);
            int cg = bn + wc * 64 + (lane & 15) * 4;
            if (cg + 3 < N) {
                *reinterpret_cast<f32x4*>(&C[(size_t)rg * N + cg]) = vv;
            } else {
                #pragma unroll
                for (int e = 0; e < 4; ++e)
                    if (cg + e < N) C[(size_t)rg * N + cg + e] = vv[e];
            }
        }
    }
}

// ---- Plain bf16 MFMA GEMM from fp32 (fallback logits path) ----
__global__ __launch_bounds__(256) void mfma_gemm(const float* __restrict__ A,
                                                 const float* __restrict__ B,
                                                 float* __restrict__ C,
                                                 int M, int N, int K) {
    __shared__ __align__(16) unsigned short As[MB * LDT];
    __shared__ __align__(16) unsigned short Bs[NB * LDT];
    int tid = threadIdx.x;
    int bm = blockIdx.y * MB, bn = blockIdx.x * NB;
    int srow = tid >> 1, shalf = tid & 1;
    int lane = tid & 63, w = tid >> 6;
    int wr = w >> 1, wc = w & 1;
    int r0 = (lane >> 4) * 4, c0 = lane & 15;
    int kb = (lane >> 4) * 8;

    f32x4 acc[4][4] = {};

    for (int kk = 0; kk < K; kk += KB) {
        stage_tile(As, A + (size_t)(bm + srow) * K + kk + shalf * 16, true, srow, shalf);
        bool bval = (bn + srow) < N;
        stage_tile(Bs, B + (size_t)(bn + srow) * K + kk + shalf * 16, bval, srow, shalf);
        __syncthreads();
        bf16x8 af[4], bf[4];
        #pragma unroll
        for (int m = 0; m < 4; ++m)
            af[m] = *reinterpret_cast<const bf16x8*>(&As[(wr * 64 + m * 16 + c0) * LDT + kb]);
        #pragma unroll
        for (int n = 0; n < 4; ++n)
            bf[n] = *reinterpret_cast<const bf16x8*>(&Bs[(wc * 64 + n * 16 + c0) * LDT + kb]);
        #pragma unroll
        for (int m = 0; m < 4; ++m)
            #pragma unroll
            for (int n = 0; n < 4; ++n)
                acc[m][n] = __builtin_amdgcn_mfma_f32_16x16x32_bf16(af[m], bf[n], acc[m][n], 0, 0, 0);
        __syncthreads();
    }

    #pragma unroll
    for (int n = 0; n < 4; ++n) {
        int col = bn + wc * 64 + n * 16 + c0;
        if (col < N) {
            #pragma unroll
            for (int m = 0; m < 4; ++m)
                #pragma unroll
                for (int r = 0; r < 4; ++r) {
                    int row = bm + wr * 64 + m * 16 + r0 + r;
                    C[(size_t)row * N + col] = acc[m][n][r];
                }
        }
    }
}

// ---- Split GEMM, pre-split A + fp32 B, K-SPLIT PARTIAL, register prefetch ----
__global__ __launch_bounds__(256) void mfma_gemm_pA_part(const unsigned short* __restrict__ Ahp,
                                                         const unsigned short* __restrict__ Alp,
                                                         const float* __restrict__ B,
                                                         float* __restrict__ part,
                                                         int M, int N, int K, int KSPLIT) {
    __shared__ __align__(16) unsigned short SMEM[4 * MB * LDT];
    unsigned short* Ah = SMEM;
    unsigned short* Al = SMEM + MB * LDT;
    unsigned short* Bh = SMEM + 2 * MB * LDT;
    unsigned short* Bl = SMEM + 3 * MB * LDT;
    int tid = threadIdx.x;
    int bm = blockIdx.y * MB, bn = blockIdx.x * NB;
    int kc = blockIdx.z;
    int chunk = K / KSPLIT;
    int kbeg = kc * chunk;
    int srow = tid >> 1, shalf = tid & 1;
    int lane = tid & 63, w = tid >> 6;
    int wr = w >> 1, wc = w & 1;
    int r0 = (lane >> 4) * 4, c0 = lane & 15;
    int kb = (lane >> 4) * 8;

    const unsigned short* ApH = Ahp + (size_t)(bm + srow) * K + shalf * 16;
    const unsigned short* ApL = Alp + (size_t)(bm + srow) * K + shalf * 16;
    const float* Bp = B + (size_t)(bn + srow) * K + shalf * 16;

    uint4 rah0 = reinterpret_cast<const uint4*>(ApH + kbeg)[0];
    uint4 rah1 = reinterpret_cast<const uint4*>(ApH + kbeg)[1];
    uint4 ral0 = reinterpret_cast<const uint4*>(ApL + kbeg)[0];
    uint4 ral1 = reinterpret_cast<const uint4*>(ApL + kbeg)[1];
    float4 rbv0 = reinterpret_cast<const float4*>(Bp + kbeg)[0];
    float4 rbv1 = reinterpret_cast<const float4*>(Bp + kbeg)[1];
    float4 rbv2 = reinterpret_cast<const float4*>(Bp + kbeg)[2];
    float4 rbv3 = reinterpret_cast<const float4*>(Bp + kbeg)[3];

    f32x4 acc[4][4] = {};

    for (int kk = kbeg; kk < kbeg + chunk; kk += KB) {
        uint4* dah = reinterpret_cast<uint4*>(&Ah[srow * LDT + shalf * 16]);
        dah[0] = rah0; dah[1] = rah1;
        uint4* dal = reinterpret_cast<uint4*>(&Al[srow * LDT + shalf * 16]);
        dal[0] = ral0; dal[1] = ral1;
        float4 rbv[4] = {rbv0, rbv1, rbv2, rbv3};
        stage_split_regs(Bh, Bl, rbv, srow, shalf);
        __syncthreads();
        if (kk + KB < kbeg + chunk) {
            int kn = kk + KB;
            rah0 = reinterpret_cast<const uint4*>(ApH + kn)[0];
            rah1 = reinterpret_cast<const uint4*>(ApH + kn)[1];
            ral0 = reinterpret_cast<const uint4*>(ApL + kn)[0];
            ral1 = reinterpret_cast<const uint4*>(ApL + kn)[1];
            rbv0 = reinterpret_cast<const float4*>(Bp + kn)[0];
            rbv1 = reinterpret_cast<const float4*>(Bp + kn)[1];
            rbv2 = reinterpret_cast<const float4*>(Bp + kn)[2];
            rbv3 = reinterpret_cast<const float4*>(Bp + kn)[3];
        }
        bf16x8 ah[4], al[4], bh[4], bl[4];
        #pragma unroll
        for (int m = 0; m < 4; ++m) {
            int o = (wr * 64 + m * 16 + c0) * LDT + kb;
            ah[m] = *reinterpret_cast<const bf16x8*>(&Ah[o]);
            al[m] = *reinterpret_cast<const bf16x8*>(&Al[o]);
        }
        #pragma unroll
        for (int n = 0; n < 4; ++n) {
            int o = (wc * 64 + n * 16 + c0) * LDT + kb;
            bh[n] = *reinterpret_cast<const bf16x8*>(&Bh[o]);
            bl[n] = *reinterpret_cast<const bf16x8*>(&Bl[o]);
        }
        #pragma unroll
        for (int m = 0; m < 4; ++m)
            #pragma unroll
            for (int n = 0; n < 4; ++n) {
                acc[m][n] = __builtin_amdgcn_mfma_f32_16x16x32_bf16(al[m], bh[n], acc[m][n], 0, 0, 0);
                acc[m][n] = __builtin_amdgcn_mfma_f32_16x16x32_bf16(ah[m], bl[n], acc[m][n], 0, 0, 0);
                acc[m][n] = __builtin_amdgcn_mfma_f32_16x16x32_bf16(ah[m], bh[n], acc[m][n], 0, 0, 0);
            }
        __syncthreads();
    }

    float* Ct = reinterpret_cast<float*>(SMEM);
    float* cw = Ct + w * 1024;
    float* P = part + (size_t)kc * M * N;
    #pragma unroll
    for (int m = 0; m < 4; ++m) {
        #pragma unroll
        for (int n = 0; n < 4; ++n)
            #pragma unroll
            for (int r = 0; r < 4; ++r)
                cw[(r0 + r) * 64 + n * 16 + c0] = acc[m][n][r];
        #pragma unroll
        for (int ch = 0; ch < 4; ++ch) {
            f32x4 vv = *reinterpret_cast<const f32x4*>(&cw[ch * 256 + lane * 4]);
            int rg = bm + wr * 64 + m * 16 + ch * 4 + (lane >> 4);
            int cg = bn + wc * 64 + (lane & 15) * 4;
            *reinterpret_cast<f32x4*>(&P[(size_t)rg * N + cg]) = vv;
        }
    }
}

// ---- Dense reduce (fp32 out, no act): qkv ----
__global__ __launch_bounds__(256) void reduce_dense(const float* __restrict__ part,
                                                    const float* __restrict__ bias,
                                                    float* __restrict__ C,
                                                    long MN, int N, int KSPLIT) {
    long stride = (long)gridDim.x * 256 * 4;
    for (long i = ((long)blockIdx.x * 256 + threadIdx.x) * 4; i < MN; i += stride) {
        float4 v = *reinterpret_cast<const float4*>(part + i);
        for (int kc = 1; kc < KSPLIT; ++kc) {
            float4 p = *reinterpret_cast<const float4*>(part + (size_t)kc * MN + i);
            v.x += p.x; v.y += p.y; v.z += p.z; v.w += p.w;
        }
        int col = (int)(i % N);
        float4 b = *reinterpret_cast<const float4*>(bias + col);
        v.x += b.x; v.y += b.y; v.z += b.z; v.w += b.w;
        *reinterpret_cast<float4*>(C + i) = v;
    }
}

// ---- FFN1 reduce: gelu(Σ parts + bias) -> hi/lo bf16 ----
__global__ __launch_bounds__(256) void reduce_gelu_bf(const float* __restrict__ part,
                                                      const float* __restrict__ bias,
                                                      unsigned short* __restrict__ outh,
                                                      unsigned short* __restrict__ outl,
                                                      long MN, int N, int KSPLIT) {
    long stride = (long)gridDim.x * 256 * 4;
    for (long i = ((long)blockIdx.x * 256 + threadIdx.x) * 4; i < MN; i += stride) {
        float4 v = *reinterpret_cast<const float4*>(part + i);
        for (int kc = 1; kc < KSPLIT; ++kc) {
            float4 p = *reinterpret_cast<const float4*>(part + (size_t)kc * MN + i);
            v.x += p.x; v.y += p.y; v.z += p.z; v.w += p.w;
        }
        int col = (int)(i % N);
        float4 b = *reinterpret_cast<const float4*>(bias + col);
        float f[4];
        f[0] = gelu_exact(v.x + b.x); f[1] = gelu_exact(v.y + b.y);
        f[2] = gelu_exact(v.z + b.z); f[3] = gelu_exact(v.w + b.w);
        union { unsigned short s[4]; uint2 u; } ph, pl;
        #pragma unroll
        for (int e = 0; e < 4; ++e) {
            unsigned short hb = f2bf(f[e]);
            ph.s[e] = hb;
            pl.s[e] = f2bf(f[e] - bf2f_bits(hb));
        }
        *reinterpret_cast<uint2*>(outh + i) = ph.u;
        *reinterpret_cast<uint2*>(outl + i) = pl.u;
    }
}

// ---- Fused reduce(+bias+res into h) + LN -> xn (fp32) + xn hi/lo ----
__global__ __launch_bounds__(256) void reduce_ln(const float* __restrict__ part,
                                                 const float* __restrict__ bias,
                                                 float* __restrict__ h,
                                                 const float* __restrict__ g,
                                                 const float* __restrict__ b,
                                                 float* __restrict__ xn,
                                                 unsigned short* __restrict__ xnh,
                                                 unsigned short* __restrict__ xnl,
                                                 int KSPLIT) {
    const long MN = (long)NT * Dm;
    int t = blockIdx.x, tid = threadIdx.x;
    float v[3];
    #pragma unroll
    for (int j = 0; j < 3; ++j) {
        int col = tid + j * 256;
        long idx = (long)t * Dm + col;
        float s = part[idx];
        for (int kc = 1; kc < KSPLIT; ++kc) s += part[(size_t)kc * MN + idx];
        s += bias[col] + h[idx];
        h[idx] = s;
        v[j] = s;
    }
    __shared__ float red[256];
    red[tid] = v[0] + v[1] + v[2];
    __syncthreads();
    for (int off = 128; off > 0; off >>= 1) {
        if (tid < off) red[tid] += red[tid + off];
        __syncthreads();
    }
    float mean = red[0] * (1.0f / Dm);
    __syncthreads();
    float d0 = v[0] - mean, d1 = v[1] - mean, d2 = v[2] - mean;
    red[tid] = d0 * d0 + d1 * d1 + d2 * d2;
    __syncthreads();
    for (int off = 128; off > 0; off >>= 1) {
        if (tid < off) red[tid] += red[tid + off];
        __syncthreads();
    }
    float inv = rsqrtf(red[0] * (1.0f / Dm) + 1e-5f);
    float o0 = d0 * inv * g[tid]       + b[tid];
    float o1 = d1 * inv * g[tid + 256] + b[tid + 256];
    float o2 = d2 * inv * g[tid + 512] + b[tid + 512];
    long base = (size_t)t * Dm;
    xn[base + tid] = o0; xn[base + tid + 256] = o1; xn[base + tid + 512] = o2;
    unsigned short h0 = f2bf(o0), h1 = f2bf(o1), h2 = f2bf(o2);
    xnh[base + tid] = h0; xnh[base + tid + 256] = h1; xnh[base + tid + 512] = h2;
    xnl[base + tid]       = f2bf(o0 - bf2f_bits(h0));
    xnl[base + tid + 256] = f2bf(o1 - bf2f_bits(h1));
    xnl[base + tid + 512] = f2bf(o2 - bf2f_bits(h2));
}

// ---- Fused MoE combine + LN -> xn + hi/lo ----
__global__ __launch_bounds__(256) void combine_ln(float* __restrict__ h,
                                                  const float* __restrict__ ye,
                                                  const float* __restrict__ g,
                                                  const float* __restrict__ b,
                                                  float* __restrict__ xn,
                                                  unsigned short* __restrict__ xnh,
                                                  unsigned short* __restrict__ xnl) {
    int t = blockIdx.x, tid = threadIdx.x;
    float v[3];
    #pragma unroll
    for (int j = 0; j < 3; ++j) {
        int col = tid + j * 256;
        long idx = (long)t * Dm + col;
        float s = h[idx] + ye[(size_t)(t * 2) * Dm + col] + ye[(size_t)(t * 2 + 1) * Dm + col];
        h[idx] = s;
        v[j] = s;
    }
    __shared__ float red[256];
    red[tid] = v[0] + v[1] + v[2];
    __syncthreads();
    for (int off = 128; off > 0; off >>= 1) {
        if (tid < off) red[tid] += red[tid + off];
        __syncthreads();
    }
    float mean = red[0] * (1.0f / Dm);
    __syncthreads();
    float d0 = v[0] - mean, d1 = v[1] - mean, d2 = v[2] - mean;
    red[tid] = d0 * d0 + d1 * d1 + d2 * d2;
    __syncthreads();
    for (int off = 128; off > 0; off >>= 1) {
        if (tid < off) red[tid] += red[tid + off];
        __syncthreads();
    }
    float inv = rsqrtf(red[0] * (1.0f / Dm) + 1e-5f);
    float o0 = d0 * inv * g[tid]       + b[tid];
    float o1 = d1 * inv * g[tid + 256] + b[tid + 256];
    float o2 = d2 * inv * g[tid + 512] + b[tid + 512];
    long base = (size_t)t * Dm;
    xn[base + tid] = o0; xn[base + tid + 256] = o1; xn[base + tid + 512] = o2;
    unsigned short h0 = f2bf(o0), h1 = f2bf(o1), h2 = f2bf(o2);
    xnh[base + tid] = h0; xnh[base + tid + 256] = h1; xnh[base + tid + 512] = h2;
    xnl[base + tid]       = f2bf(o0 - bf2f_bits(h0));
    xnl[base + tid + 256] = f2bf(o1 - bf2f_bits(h1));
    xnl[base + tid + 512] = f2bf(o2 - bf2f_bits(h2));
}

// ---------------- Flash attention, split-bf16 MFMA; outputs hi/lo bf16 ----------------
#define LDA 72
__device__ __forceinline__ void stage16a(unsigned short* dh, unsigned short* dl,
                                         const float* src) {
    union { unsigned short s[8]; uint4 v; } h0, h1, l0, l1;
    const float4* s4 = reinterpret_cast<const float4*>(src);
    #pragma unroll
    for (int q = 0; q < 4; ++q) {
        float4 f = s4[q];
        float vv[4] = {f.x, f.y, f.z, f.w};
        #pragma unroll
        for (int j = 0; j < 4; ++j) {
            int idx = q * 4 + j;
            unsigned short hb = f2bf(vv[j]);
            unsigned short lb = f2bf(vv[j] - bf2f_bits(hb));
            if (idx < 8) { h0.s[idx] = hb; l0.s[idx] = lb; }
            else         { h1.s[idx - 8] = hb; l1.s[idx - 8] = lb; }
        }
    }
    reinterpret_cast<uint4*>(dh)[0] = h0.v; reinterpret_cast<uint4*>(dh)[1] = h1.v;
    reinterpret_cast<uint4*>(dl)[0] = l0.v; reinterpret_cast<uint4*>(dl)[1] = l1.v;
}

__global__ __launch_bounds__(256) void attn_flash(const float* __restrict__ qkv,
                                                  unsigned short* __restrict__ aoh,
                                                  unsigned short* __restrict__ aol) {
    int qt = blockIdx.x;
    int bh = blockIdx.y;
    int b = bh / NHm, hh = bh % NHm;
    const int g0 = b * Tm;
    const int hoff = hh * 64;
    int tid = threadIdx.x;
    int lane = tid & 63, w = tid >> 6;
    int c0 = lane & 15, hi4 = lane >> 4;
    int kb = hi4 * 8;

    __shared__ __align__(16) unsigned short Qh[64 * LDA], Ql[64 * LDA];
    __shared__ __align__(16) unsigned short Kh[64 * LDA], Kl[64 * LDA];
    __shared__ __align__(16) unsigned short Vh[64 * LDA], Vl[64 * LDA];
    __shared__ __align__(16) unsigned short Ph[4][16 * LDA], Pl[4][16 * LDA];

    {
        int srow = tid >> 2, q = tid & 3;
        stage16a(&Qh[srow * LDA + q * 16], &Ql[srow * LDA + q * 16],
                 qkv + (size_t)(g0 + qt * 64 + srow) * (3 * Dm) + hoff + q * 16);
    }
    __syncthreads();

    f32x4 acc_o[4] = {};
    float m_r[4] = {-1e30f, -1e30f, -1e30f, -1e30f};
    float l_r[4] = {0.f, 0.f, 0.f, 0.f};

    for (int kt = 0; kt <= qt; ++kt) {
        {
            int srow = tid >> 2, q = tid & 3;
            stage16a(&Kh[srow * LDA + q * 16], &Kl[srow * LDA + q * 16],
                     qkv + (size_t)(g0 + kt * 64 + srow) * (3 * Dm) + Dm + hoff + q * 16);
        }
        {
            int d = lane, kg = w;
            const float* vbase = qkv + (size_t)(g0 + kt * 64 + kg * 16) * (3 * Dm) + 2 * Dm + hoff + d;
            #pragma unroll
            for (int k2 = 0; k2 < 16; ++k2) {
                float v = vbase[(size_t)k2 * (3 * Dm)];
                unsigned short hb = f2bf(v);
                Vh[d * LDA + kg * 16 + k2] = hb;
                Vl[d * LDA + kg * 16 + k2] = f2bf(v - bf2f_bits(hb));
            }
        }
        __syncthreads();

        f32x4 sAcc[4] = {};
        #pragma unroll
        for (int kk2 = 0; kk2 < 64; kk2 += 32) {
            bf16x8 ah = *reinterpret_cast<const bf16x8*>(&Qh[(w * 16 + c0) * LDA + kk2 + kb]);
            bf16x8 al = *reinterpret_cast<const bf16x8*>(&Ql[(w * 16 + c0) * LDA + kk2 + kb]);
            #pragma unroll
            for (int n = 0; n < 4; ++n) {
                bf16x8 bh_ = *reinterpret_cast<const bf16x8*>(&Kh[(n * 16 + c0) * LDA + kk2 + kb]);
                bf16x8 bl_ = *reinterpret_cast<const bf16x8*>(&Kl[(n * 16 + c0) * LDA + kk2 + kb]);
                sAcc[n] = __builtin_amdgcn_mfma_f32_16x16x32_bf16(al, bh_, sAcc[n], 0, 0, 0);
                sAcc[n] = __builtin_amdgcn_mfma_f32_16x16x32_bf16(ah, bl_, sAcc[n], 0, 0, 0);
                sAcc[n] = __builtin_amdgcn_mfma_f32_16x16x32_bf16(ah, bh_, sAcc[n], 0, 0, 0);
            }
        }

        float p[4][4];
        float smax[4] = {-3e38f, -3e38f, -3e38f, -3e38f};
        #pragma unroll
        for (int n = 0; n < 4; ++n)
            #pragma unroll
            for (int r = 0; r < 4; ++r) {
                float s = sAcc[n][r] * 0.125f;
                if (kt == qt) {
                    int kg = n * 16 + c0;
                    int qg = w * 16 + hi4 * 4 + r;
                    if (kg > qg) s = -3e38f;
                }
                p[n][r] = s;
                smax[r] = fmaxf(smax[r], s);
            }
        #pragma unroll
        for (int off = 1; off < 16; off <<= 1)
            #pragma unroll
            for (int r = 0; r < 4; ++r)
                smax[r] = fmaxf(smax[r], __shfl_xor(smax[r], off));
        float f_r[4], lsum[4];
        #pragma unroll
        for (int r = 0; r < 4; ++r) {
            float mn = fmaxf(m_r[r], smax[r]);
            f_r[r] = expf(m_r[r] - mn);
            m_r[r] = mn;
        }
        #pragma unroll
        for (int n = 0; n < 4; ++n)
            #pragma unroll
            for (int r = 0; r < 4; ++r)
                p[n][r] = expf(p[n][r] - m_r[r]);
        #pragma unroll
        for (int r = 0; r < 4; ++r)
            lsum[r] = p[0][r] + p[1][r] + p[2][r] + p[3][r];
        #pragma unroll
        for (int off = 1; off < 16; off <<= 1)
            #pragma unroll
            for (int r = 0; r < 4; ++r)
                lsum[r] += __shfl_xor(lsum[r], off);
        #pragma unroll
        for (int r = 0; r < 4; ++r)
            l_r[r] = l_r[r] * f_r[r] + lsum[r];
        #pragma unroll
        for (int n = 0; n < 4; ++n)
            #pragma unroll
            for (int r = 0; r < 4; ++r)
                acc_o[n][r] *= f_r[r];

        #pragma unroll
        for (int n = 0; n < 4; ++n)
            #pragma unroll
            for (int r = 0; r < 4; ++r) {
                unsigned short hb = f2bf(p[n][r]);
                int o = (hi4 * 4 + r) * LDA + n * 16 + c0;
                Ph[w][o] = hb;
                Pl[w][o] = f2bf(p[n][r] - bf2f_bits(hb));
            }

        #pragma unroll
        for (int kk2 = 0; kk2 < 64; kk2 += 32) {
            bf16x8 pah = *reinterpret_cast<const bf16x8*>(&Ph[w][c0 * LDA + kk2 + kb]);
            bf16x8 pal = *reinterpret_cast<const bf16x8*>(&Pl[w][c0 * LDA + kk2 + kb]);
            #pragma unroll
            for (int n = 0; n < 4; ++n) {
                bf16x8 vbh = *reinterpret_cast<const bf16x8*>(&Vh[(n * 16 + c0) * LDA + kk2 + kb]);
                bf16x8 vbl = *reinterpret_cast<const bf16x8*>(&Vl[(n * 16 + c0) * LDA + kk2 + kb]);
                acc_o[n] = __builtin_amdgcn_mfma_f32_16x16x32_bf16(pal, vbh, acc_o[n], 0, 0, 0);
                acc_o[n] = __builtin_amdgcn_mfma_f32_16x16x32_bf16(pah, vbl, acc_o[n], 0, 0, 0);
                acc_o[n] = __builtin_amdgcn_mfma_f32_16x16x32_bf16(pah, vbh, acc_o[n], 0, 0, 0);
            }
        }
        __syncthreads();
    }

    float inv[4];
    #pragma unroll
    for (int r = 0; r < 4; ++r) inv[r] = 1.0f / l_r[r];
    #pragma unroll
    for (int n = 0; n < 4; ++n)
        #pragma unroll
        for (int r = 0; r < 4; ++r) {
            int row = g0 + qt * 64 + w * 16 + hi4 * 4 + r;
            float v = acc_o[n][r] * inv[r];
            unsigned short hb = f2bf(v);
            size_t idx = (size_t)row * Dm + hoff + n * 16 + c0;
            aoh[idx] = hb;
            aol[idx] = f2bf(v - bf2f_bits(hb));
        }
}

// ---------------- MoE router: wave-parallel (fp32 xn) ----------------
__global__ __launch_bounds__(256) void router_kernel(const float* __restrict__ xn,
                                                     const float* __restrict__ gw,
                                                     int* __restrict__ topi,
                                                     float* __restrict__ topw) {
    int t = blockIdx.x * 4 + (threadIdx.x >> 6);
    int lane = threadIdx.x & 63;
    const float4* x4 = reinterpret_cast<const float4*>(xn + (size_t)t * Dm);
    float4 xv[3];
    #pragma unroll
    for (int i = 0; i < 3; ++i) xv[i] = x4[lane + i * 64];

    float l[Em];
    #pragma unroll
    for (int e = 0; e < Em; ++e) {
        const float4* w4 = reinterpret_cast<const float4*>(gw + (size_t)e * Dm);
        float dot = 0.f;
        #pragma unroll
        for (int i = 0; i < 3; ++i) {
            float4 wv = w4[lane + i * 64];
            dot += xv[i].x * wv.x + xv[i].y * wv.y + xv[i].z * wv.z + xv[i].w * wv.w;
        }
        #pragma unroll
        for (int off = 32; off > 0; off >>= 1) dot += __shfl_xor(dot, off);
        l[e] = dot;
    }
    if (lane == 0) {
        int i1 = 0;
        #pragma unroll
        for (int e = 1; e < Em; ++e) if (l[e] > l[i1]) i1 = e;
        int i2 = (i1 == 0) ? 1 : 0;
        #pragma unroll
        for (int e = 0; e < Em; ++e) if (e != i1 && l[e] > l[i2]) i2 = e;
        float w1 = 1.0f / (1.0f + expf(l[i2] - l[i1]));
        topi[t * 2] = i1; topi[t * 2 + 1] = i2;
        topw[t * 2] = w1; topw[t * 2 + 1] = 1.0f - w1;
    }
}

// ---------------- Route build ----------------
__global__ __launch_bounds__(256) void route_build_kernel(const int* __restrict__ topi,
                                                          int* __restrict__ g_cnt,
                                                          int* __restrict__ g_off,
                                                          int* __restrict__ bucket) {
    __shared__ int cnt[Em], off[Em], pos[Em];
    int tid = threadIdx.x;
    if (tid < Em) cnt[tid] = 0;
    __syncthreads();
    for (int ts = tid; ts < NAS; ts += 256) atomicAdd(&cnt[topi[ts]], 1);
    __syncthreads();
    if (tid == 0) {
        int acc = 0;
        for (int e = 0; e < Em; ++e) { off[e] = acc; pos[e] = acc; acc += cnt[e]; }
    }
    __syncthreads();
    for (int ts = tid; ts < NAS; ts += 256) {
        int e = topi[ts];
        int p = atomicAdd(&pos[e], 1);
        bucket[p] = ts;
    }
    if (tid < Em) { g_cnt[tid] = cnt[tid]; g_off[tid] = off[tid]; }
}

// ---------------- Grouped MoE GEMM1: A = xn hi/lo, B = fp32 weights; out heg hi/lo ----
template<int SPLIT>
__global__ __launch_bounds__(256) void moe_mfma_gemm1(const unsigned short* __restrict__ xnh,
                                                      const unsigned short* __restrict__ xnl,
                                                      const float* __restrict__ W1all,
                                                      const float* __restrict__ B1all,
                                                      const int* __restrict__ bucket,
                                                      const int* __restrict__ cnt,
                                                      const int* __restrict__ off,
                                                      unsigned short* __restrict__ hegh,
                                                      unsigned short* __restrict__ hegl) {
    int e = blockIdx.z;
    int count = cnt[e];
    int mbase = blockIdx.y * MB;
    if (mbase >= count) return;
    int base = off[e];

    __shared__ __align__(16) unsigned short Ah[MB * LDT];
    __shared__ __align__(16) unsigned short Bh[NB * LDT];
    __shared__ __align__(16) unsigned short Al[SPLIT ? MB * LDT : 8];
    __shared__ __align__(16) unsigned short Bl[SPLIT ? NB * LDT : 8];
    __shared__ int toks[MB];
    int tid = threadIdx.x;
    int bn = blockIdx.x * NB;
    int srow = tid >> 1, shalf = tid & 1;
    int lane = tid & 63, w = tid >> 6;
    int wr = w >> 1, wc = w & 1;
    int r0 = (lane >> 4) * 4, c0 = lane & 15;
    int kb = (lane >> 4) * 8;
    if (tid < MB) {
        int p = mbase + tid;
        toks[tid] = (p < count) ? (bucket[base + p] >> 1) : -1;
    }
    __syncthreads();

    f32x4 acc[4][4] = {};
    const float* W = W1all + (size_t)e * Hm * Dm;
    int t = toks[srow];
    for (int kk = 0; kk < Dm; kk += KB) {
        size_t aoff = (size_t)t * Dm + kk + shalf * 16;
        stage_tile_copy(Ah, xnh + aoff, t >= 0, srow, shalf);
        if (SPLIT) {
            stage_tile_copy(Al, xnl + aoff, t >= 0, srow, shalf);
            stage_tile_split(Bh, Bl, W + (size_t)(bn + srow) * Dm + kk + shalf * 16, true, srow, shalf);
        } else {
            stage_tile(Bh, W + (size_t)(bn + srow) * Dm + kk + shalf * 16, true, srow, shalf);
        }
        __syncthreads();
        bf16x8 ah[4], bh[4], al[4], bl[4];
        #pragma unroll
        for (int m = 0; m < 4; ++m) {
            int o = (wr * 64 + m * 16 + c0) * LDT + kb;
            ah[m] = *reinterpret_cast<const bf16x8*>(&Ah[o]);
            if (SPLIT) al[m] = *reinterpret_cast<const bf16x8*>(&Al[o]);
        }
        #pragma unroll
        for (int n = 0; n < 4; ++n) {
            int o = (wc * 64 + n * 16 + c0) * LDT + kb;
            bh[n] = *reinterpret_cast<const bf16x8*>(&Bh[o]);
            if (SPLIT) bl[n] = *reinterpret_cast<const bf16x8*>(&Bl[o]);
        }
        #pragma unroll
        for (int m = 0; m < 4; ++m)
            #pragma unroll
            for (int n = 0; n < 4; ++n) {
                if (SPLIT) {
                    acc[m][n] = __builtin_amdgcn_mfma_f32_16x16x32_bf16(al[m], bh[n], acc[m][n], 0, 0, 0);
                    acc[m][n] = __builtin_amdgcn_mfma_f32_16x16x32_bf16(ah[m], bl[n], acc[m][n], 0, 0, 0);
                }
                acc[m][n] = __builtin_amdgcn_mfma_f32_16x16x32_bf16(ah[m], bh[n], acc[m][n], 0, 0, 0);
            }
        __syncthreads();
    }

    const float* b1 = B1all + (size_t)e * Hm;
    #pragma unroll
    for (int n = 0; n < 4; ++n) {
        int col = bn + wc * 64 + n * 16 + c0;
        float bv = b1[col];
        #pragma unroll
        for (int m = 0; m < 4; ++m) {
            #pragma unroll
            for (int r = 0; r < 4; ++r) {
                int p = mbase + wr * 64 + m * 16 + r0 + r;
                if (p < count) {
                    float v = gelu_exact(acc[m][n][r] + bv);
                    unsigned short hb = f2bf(v);
                    size_t idx = (size_t)(base + p) * Hm + col;
                    hegh[idx] = hb;
                    hegl[idx] = f2bf(v - bf2f_bits(hb));
                }
            }
        }
    }
}

// ---------------- Grouped MoE GEMM2: A = heg hi/lo, B = fp32; K-SPLIT partial ----
template<int SPLIT>
__global__ __launch_bounds__(256) void moe_gemm2_part(const unsigned short* __restrict__ hegh,
                                                      const unsigned short* __restrict__ hegl,
                                                      const float* __restrict__ W2all,
                                                      const int* __restrict__ cnt,
                                                      const int* __restrict__ off,
                                                      float* __restrict__ part,
                                                      int KSPLIT) {
    int e = blockIdx.z;
    int count = cnt[e];
    int my = blockIdx.y;
    int kc = my % KSPLIT, mb = my / KSPLIT;
    int mbase = mb * MB;
    if (mbase >= count) return;
    int base = off[e];
    int chunk = Hm / KSPLIT;
    int kbeg = kc * chunk;

    __shared__ __align__(16) unsigned short Ah[MB * LDT];
    __shared__ __align__(16) unsigned short Bh[NB * LDT];
    __shared__ __align__(16) unsigned short Al[SPLIT ? MB * LDT : 8];
    __shared__ __align__(16) unsigned short Bl[SPLIT ? NB * LDT : 8];
    int tid = threadIdx.x;
    int bn = blockIdx.x * NB;
    int srow = tid >> 1, shalf = tid & 1;
    int lane = tid & 63, w = tid >> 6;
    int wr = w >> 1, wc = w & 1;
    int r0 = (lane >> 4) * 4, c0 = lane & 15;
    int kb = (lane >> 4) * 8;

    f32x4 acc[4][4] = {};
    const float* W = W2all + (size_t)e * Dm * Hm;
    bool aval = (mbase + srow) < count;
    for (int kk = kbeg; kk < kbeg + chunk; kk += KB) {
        size_t aoff = (size_t)(base + mbase + srow) * Hm + kk + shalf * 16;
        stage_tile_copy(Ah, hegh + aoff, aval, srow, shalf);
        if (SPLIT) {
            stage_tile_copy(Al, hegl + aoff, aval, srow, shalf);
            stage_tile_split(Bh, Bl, W + (size_t)(bn + srow) * Hm + kk + shalf * 16, true, srow, shalf);
        } else {
            stage_tile(Bh, W + (size_t)(bn + srow) * Hm + kk + shalf * 16, true, srow, shalf);
        }
        __syncthreads();
        bf16x8 ah[4], bh[4], al[4], bl[4];
        #pragma unroll
        for (int m = 0; m < 4; ++m) {
            int o = (wr * 64 + m * 16 + c0) * LDT + kb;
            ah[m] = *reinterpret_cast<const bf16x8*>(&Ah[o]);
            if (SPLIT) al[m] = *reinterpret_cast<const bf16x8*>(&Al[o]);
        }
        #pragma unroll
        for (int n = 0; n < 4; ++n) {
            int o = (wc * 64 + n * 16 + c0) * LDT + kb;
            bh[n] = *reinterpret_cast<const bf16x8*>(&Bh[o]);
            if (SPLIT) bl[n] = *reinterpret_cast<const bf16x8*>(&Bl[o]);
        }
        #pragma unroll
        for (int m = 0; m < 4; ++m)
            #pragma unroll
            for (int n = 0; n < 4; ++n) {
                if (SPLIT) {
                    acc[m][n] = __builtin_amdgcn_mfma_f32_16x16x32_bf16(al[m], bh[n], acc[m][n], 0, 0, 0);
                    acc[m][n] = __builtin_amdgcn_mfma_f32_16x16x32_bf16(ah[m], bl[n], acc[m][n], 0, 0, 0);
                }
                acc[m][n] = __builtin_amdgcn_mfma_f32_16x16x32_bf16(ah[m], bh[n], acc[m][n], 0, 0, 0);
            }
        __syncthreads();
    }

    float* P = part + (size_t)kc * NAS * Dm;
    #pragma unroll
    for (int n = 0; n < 4; ++n) {
        int col = bn + wc * 64 + n * 16 + c0;
        #pragma unroll
        for (int m = 0; m < 4; ++m) {
            #pragma unroll
            for (int r = 0; r < 4; ++r) {
                int p = mbase + wr * 64 + m * 16 + r0 + r;
                if (p < count)
                    P[(size_t)(base + p) * Dm + col] = acc[m][n][r];
            }
        }
    }
}

// ---- MoE reduce: ye[ts] = topw[ts] * (Σ parts + b2[e]) ----
__global__ __launch_bounds__(256) void moe_reduce(const float* __restrict__ part,
                                                  const float* __restrict__ B2all,
                                                  const int* __restrict__ bucket,
                                                  const int* __restrict__ topi,
                                                  const float* __restrict__ topw,
                                                  float* __restrict__ ye, int KSPLIT) {
    const long MN = (long)NAS * Dm;
    long stride = (long)gridDim.x * 256 * 4;
    for (long i = ((long)blockIdx.x * 256 + threadIdx.x) * 4; i < MN; i += stride) {
        int p = (int)(i / Dm), col = (int)(i % Dm);
        int ts = bucket[p];
        int e = topi[ts];
        float wgt = topw[ts];
        float4 v = *reinterpret_cast<const float4*>(part + i);
        for (int kc = 1; kc < KSPLIT; ++kc) {
            float4 q = *reinterpret_cast<const float4*>(part + (size_t)kc * MN + i);
            v.x += q.x; v.y += q.y; v.z += q.z; v.w += q.w;
        }
        float4 b = *reinterpret_cast<const float4*>(B2all + (size_t)e * Dm + col);
        float4 o;
        o.x = wgt * (v.x + b.x); o.y = wgt * (v.y + b.y);
        o.z = wgt * (v.z + b.z); o.w = wgt * (v.w + b.w);
        *reinterpret_cast<float4*>(ye + (size_t)ts * Dm + col) = o;
    }
}

// ---------------- Launch ----------------
extern "C" void kernel_launch(void* const* d_in, const int* in_sizes, int n_in,
                              void* d_out, int out_size, void* d_ws, size_t ws_size,
                              hipStream_t stream) {
    const int*   x    = (const int*)d_in[0];
    const float* emb  = (const float*)d_in[1];
    const float* wqkv = (const float*)d_in[2];
    const float* bqkv = (const float*)d_in[3];
    const float* wo   = (const float*)d_in[4];
    const float* bo   = (const float*)d_in[5];
    const float* ln1g = (const float*)d_in[6];
    const float* ln1b = (const float*)d_in[7];
    const float* ln2g = (const float*)d_in[8];
    const float* ln2b = (const float*)d_in[9];
    const float* sw1  = (const float*)d_in[10];
    const float* sb1  = (const float*)d_in[11];
    const float* sw2  = (const float*)d_in[12];
    const float* sb2  = (const float*)d_in[13];
    const float* gw   = (const float*)d_in[14];
    const float* mw1  = (const float*)d_in[15];
    const float* mb1  = (const float*)d_in[16];
    const float* mw2  = (const float*)d_in[17];
    const float* mb2  = (const float*)d_in[18];
    const float* lnfg = (const float*)d_in[19];
    const float* lnfb = (const float*)d_in[20];

    const size_t n_h    = (size_t)NT * Dm;
    const size_t n_qkv  = (size_t)NT * 3 * Dm;
    const size_t n_ye   = (size_t)NAS * Dm;
    const size_t n_part = (size_t)NT * Hm * 2;
    const size_t n_xnb  = (size_t)NT * Dm / 2;
    const size_t n_ffhb = (size_t)NT * Hm / 2;
    const size_t n_hegb = (size_t)NAS * Hm / 2;
    const size_t n_embbf = (size_t)Vm * Dm / 2;
    const size_t n_big = n_h + n_qkv + n_ye + n_part
                       + 2 * n_xnb + 2 * n_xnb
                       + 2 * n_ffhb + 2 * n_hegb;

    size_t wsf = ws_size / sizeof(float);

    float* w = (float*)d_ws;
    float* xn   = w;            w += (size_t)NT * Dm;
    float* topw = w;            w += NAS;
    int*   topi = (int*)w;      w += NAS;
    int*   bucket = (int*)w;    w += NAS;
    int*   e_cnt = (int*)w;     w += 8;
    int*   e_off = (int*)w;     w += 8;
    size_t used = (size_t)(w - (float*)d_ws);

    unsigned short* emb_bf = nullptr;
    if (wsf >= used + n_embbf + 64) {
        emb_bf = (unsigned short*)w;  w += n_embbf;
        used = (size_t)(w - (float*)d_ws);
    }

    float *h, *qkv, *ye, *part;
    unsigned short *xnh, *xnl, *aoh, *aol, *ffhh, *ffhl, *hegh, *hegl;
    float* a;
    bool arena_in_out;
    if (wsf >= used + n_big + 64) { a = w; arena_in_out = false; }
    else                          { a = (float*)d_out; arena_in_out = true; }
    h = a;      a += n_h;
    qkv = a;    a += n_qkv;
    ye = a;     a += n_ye;
    part = a;   a += n_part;
    xnh = (unsigned short*)a;  a += n_xnb;
    xnl = (unsigned short*)a;  a += n_xnb;
    aoh = (unsigned short*)a;  a += n_xnb;
    aol = (unsigned short*)a;  a += n_xnb;
    ffhh = (unsigned short*)a; a += n_ffhb;
    ffhl = (unsigned short*)a; a += n_ffhb;
    hegh = (unsigned short*)a; a += n_hegb;
    hegl = (unsigned short*)a; a += n_hegb;

    if (emb_bf) {
        long n = (long)Vm * Dm;
        cvt_bf16_kernel<<<(unsigned)((n / 8 + 255) / 256), 256, 0, stream>>>(emb, emb_bf, n);
    }

    embed_kernel<<<NT, 256, 0, stream>>>(x, emb, h);
    ln_kernel<<<NT, 256, 0, stream>>>(h, ln1g, ln1b, xn, xnh, xnl);

    const int RBLK = 2048;
    int std_i = 0, moe_i = 0;
    for (int l = 0; l < Lm; ++l) {
        const float* ng = (l < 3) ? (ln1g + (l + 1) * Dm) : lnfg;
        const float* nb = (l < 3) ? (ln1b + (l + 1) * Dm) : lnfb;

        mfma_gemm_pA_part<<<dim3((3 * Dm) / NB, NT / MB, 2), 256, 0, stream>>>(
            xnh, xnl, wqkv + (size_t)l * 3 * Dm * Dm, part, NT, 3 * Dm, Dm, 2);
        reduce_dense<<<RBLK, 256, 0, stream>>>(
            part, bqkv + (size_t)l * 3 * Dm, qkv, (long)NT * 3 * Dm, 3 * Dm, 2);
        attn_flash<<<dim3(Tm / 64, Bm * NHm), 256, 0, stream>>>(qkv, aoh, aol);
        mfma_gemm_pA_part<<<dim3(Dm / NB, NT / MB, 4), 256, 0, stream>>>(
            aoh, aol, wo + (size_t)l * Dm * Dm, part, NT, Dm, Dm, 4);
        reduce_ln<<<NT, 256, 0, stream>>>(
            part, bo + (size_t)l * Dm, h, ln2g + l * Dm, ln2b + l * Dm, xn, xnh, xnl, 4);

        if (l == 1 || l == 3) {
            router_kernel<<<NT / 4, 256, 0, stream>>>(
                xn, gw + (size_t)moe_i * Em * Dm, topi, topw);
            route_build_kernel<<<1, 256, 0, stream>>>(topi, e_cnt, e_off, bucket);
            if (l == 3) {
                moe_mfma_gemm1<0><<<dim3(Hm / NB, NAS / MB, Em), 256, 0, stream>>>(
                    xnh, xnl, mw1 + (size_t)moe_i * Em * Hm * Dm, mb1 + (size_t)moe_i * Em * Hm,
                    bucket, e_cnt, e_off, hegh, hegl);
                moe_gemm2_part<0><<<dim3(Dm / NB, (NAS / MB) * 4, Em), 256, 0, stream>>>(
                    hegh, hegl, mw2 + (size_t)moe_i * Em * Dm * Hm, e_cnt, e_off, part, 4);
            } else {
                moe_mfma_gemm1<1><<<dim3(Hm / NB, NAS / MB, Em), 256, 0, stream>>>(
                    xnh, xnl, mw1 + (size_t)moe_i * Em * Hm * Dm, mb1 + (size_t)moe_i * Em * Hm,
                    bucket, e_cnt, e_off, hegh, hegl);
                moe_gemm2_part<1><<<dim3(Dm / NB, (NAS / MB) * 4, Em), 256, 0, stream>>>(
                    hegh, hegl, mw2 + (size_t)moe_i * Em * Dm * Hm, e_cnt, e_off, part, 4);
            }
            moe_reduce<<<RBLK, 256, 0, stream>>>(
                part, mb2 + (size_t)moe_i * Em * Dm, bucket, topi, topw, ye, 4);
            combine_ln<<<NT, 256, 0, stream>>>(h, ye, ng, nb, xn, xnh, xnl);
            moe_i++;
        } else {
            mfma_gemm_pA_part<<<dim3(Hm / NB, NT / MB, 2), 256, 0, stream>>>(
                xnh, xnl, sw1 + (size_t)std_i * Hm * Dm, part, NT, Hm, Dm, 2);
            reduce_gelu_bf<<<RBLK, 256, 0, stream>>>(
                part, sb1 + (size_t)std_i * Hm, ffhh, ffhl, (long)NT * Hm, Hm, 2);
            mfma_gemm_pA_part<<<dim3(Dm / NB, NT / MB, 8), 256, 0, stream>>>(
                ffhh, ffhl, sw2 + (size_t)std_i * Dm * Hm, part, NT, Dm, Hm, 8);
            reduce_ln<<<NT, 256, 0, stream>>>(
                part, sb2 + (size_t)std_i * Dm, h, ng, nb, xn, xnh, xnl, 8);
            std_i++;
        }
    }

    if (emb_bf && !arena_in_out) {
        int nblk = (NT / MB) * ((Vm + NB - 1) / NB);
        mfma_gemm_bf<<<dim3(nblk), 256, 0, stream>>>(
            xnh, emb_bf, (float*)d_out, NT, Vm, Dm);
    } else {
        mfma_gemm<<<dim3((Vm + NB - 1) / NB, NT / MB), 256, 0, stream>>>(
            xn, emb, (float*)d_out, NT, Vm, Dm);
    }
}